// Round 11
// baseline (132.830 us; speedup 1.0000x reference)
//
#include <hip/hip_runtime.h>
#include <stdint.h>

#define DMODEL 1024
#define LSEQ   2048
#define NBATCH 2
#define NHEADS 16
#define DKH    64
#define MROWS  4096  // NBATCH*LSEQ
#define KSPLIT 2

typedef __attribute__((ext_vector_type(8))) short short8;
typedef __attribute__((ext_vector_type(4))) float f32x4;
typedef __attribute__((ext_vector_type(16))) float f32x16;
typedef __attribute__((ext_vector_type(2))) int int2v;

__device__ __forceinline__ unsigned short f2b(float f) {
  union { float f; unsigned int u; } v; v.f = f;
  unsigned int r = v.u + 0x7FFFu + ((v.u >> 16) & 1u);
  return (unsigned short)(r >> 16);
}

__device__ __forceinline__ float b2f(unsigned short u) {
  union { unsigned int i; float f; } v; v.i = ((unsigned int)u) << 16; return v.f;
}

__device__ __forceinline__ unsigned int cvtpk(float lo, float hi) {
  unsigned int r;
  asm volatile("v_cvt_pk_bf16_f32 %0, %1, %2" : "=v"(r) : "v"(lo), "v"(hi));
  return r;
}

__device__ __forceinline__ int2v pl32swap(unsigned int a, unsigned int b) {
  return __builtin_amdgcn_permlane32_swap((int)a, (int)b, false, false);
}

__device__ __forceinline__ void async16(const void* g, void* l) {
  __builtin_amdgcn_global_load_lds(
      (const __attribute__((address_space(1))) unsigned int*)g,
      (__attribute__((address_space(3))) unsigned int*)l, 16, 0, 0);
}

// one launch converts x (4 slices) + 4 weight matrices; each slice = 1M floats
__global__ void k_cvtall(const float* __restrict__ x,
                         const float* __restrict__ w0, const float* __restrict__ w1,
                         const float* __restrict__ w2, const float* __restrict__ w3,
                         unsigned short* __restrict__ xb,
                         unsigned short* __restrict__ d0, unsigned short* __restrict__ d1,
                         unsigned short* __restrict__ d2, unsigned short* __restrict__ d3) {
  const int y = blockIdx.y;
  const float* s; unsigned short* d;
  switch (y) {
    case 0: case 1: case 2: case 3:
      s = x + (size_t)y * 1048576; d = xb + (size_t)y * 1048576; break;
    case 4: s = w0; d = d0; break;
    case 5: s = w1; d = d1; break;
    case 6: s = w2; d = d2; break;
    default: s = w3; d = d3; break;
  }
  const int i = blockIdx.x * blockDim.x + threadIdx.x;
  float4 v = ((const float4*)s)[i];
  ushort4 o;
  o.x = f2b(v.x); o.y = f2b(v.y); o.z = f2b(v.z); o.w = f2b(v.w);
  ((ushort4*)d)[i] = o;
}

// acc += A[rowBase:+128, :] @ B[colBase:+128, :]^T  (both row-major [*,1024] bf16)
__device__ __forceinline__ void gemm_mainloop(
    const unsigned short* __restrict__ A, const unsigned short* __restrict__ B,
    int rowBase, int colBase, char* As, char* Bs, f32x4 acc[4][4])
{
  const int tid  = threadIdx.x;
  const int lane = tid & 63;
  const int wr   = tid >> 7;
  const int wc   = (tid >> 6) & 1;
  for (int kt = 0; kt < DMODEL / 64; ++kt) {
    const int k0 = kt * 64;
    __syncthreads();
#pragma unroll
    for (int p = 0; p < 4; ++p) {
      const int chunk = p * 256 + tid;
      const int row   = chunk >> 3;
      const int cs    = (chunk & 7) ^ (row & 7);
      async16(A + (size_t)(rowBase + row) * DMODEL + k0 + cs * 8,
              As + (p * 256 + (tid & 0xC0)) * 16);
      async16(B + (size_t)(colBase + row) * DMODEL + k0 + cs * 8,
              Bs + (p * 256 + (tid & 0xC0)) * 16);
    }
    __syncthreads();
#pragma unroll
    for (int ks = 0; ks < 2; ++ks) {
      short8 af[4], bfr[4];
#pragma unroll
      for (int m = 0; m < 4; ++m) {
        const int ra = wr * 64 + m * 16 + (lane & 15);
        af[m]  = *(const short8*)(As + ra * 128 + (((ks * 4 + (lane >> 4)) ^ (ra & 7)) * 16));
        const int rb = wc * 64 + m * 16 + (lane & 15);
        bfr[m] = *(const short8*)(Bs + rb * 128 + (((ks * 4 + (lane >> 4)) ^ (rb & 7)) * 16));
      }
#pragma unroll
      for (int m = 0; m < 4; ++m)
#pragma unroll
        for (int n = 0; n < 4; ++n)
          acc[m][n] = __builtin_amdgcn_mfma_f32_16x16x32_bf16(af[m], bfr[n], acc[m][n], 0, 0, 0);
    }
  }
}

// z=0: Q (scaled by 0.125*log2e) -> [bh][l][dk] row-major
// z=1: K -> tiled [bh][l/64][dchunk=0..7][row=l&63] 16B chunks
// z=2: V -> tiled [bh][l/64][kchunk=0..7][row=dk]   16B chunks
__global__ __launch_bounds__(256, 2) void k_gemm_qkv(
    const unsigned short* __restrict__ xb,
    const unsigned short* __restrict__ Wqb, const unsigned short* __restrict__ Wkb,
    const unsigned short* __restrict__ Wvb,
    const float* __restrict__ bq, const float* __restrict__ bk, const float* __restrict__ bv,
    unsigned short* __restrict__ Q, unsigned short* __restrict__ Ksw,
    unsigned short* __restrict__ Vsw)
{
  __shared__ char As[16384];
  __shared__ char Bs[16384];
  const int z = blockIdx.z;
  const unsigned short* W = (z == 0) ? Wqb : ((z == 1) ? Wkb : Wvb);
  const float* bias       = (z == 0) ? bq  : ((z == 1) ? bk  : bv);
  const int rowBase = blockIdx.x * 128, colBase = blockIdx.y * 128;

  f32x4 zero = {0.f, 0.f, 0.f, 0.f};
  f32x4 acc[4][4];
#pragma unroll
  for (int m = 0; m < 4; ++m)
#pragma unroll
    for (int n = 0; n < 4; ++n) acc[m][n] = zero;

  gemm_mainloop(xb, W, rowBase, colBase, As, Bs, acc);

  const int tid = threadIdx.x, lane = tid & 63;
  const int wr = tid >> 7, wc = (tid >> 6) & 1;
  const float scale = (z == 0) ? 0.18033688011112042f : 1.0f; // 0.125*log2(e)
#pragma unroll
  for (int m = 0; m < 4; ++m) {
#pragma unroll
    for (int n = 0; n < 4; ++n) {
      const int gcol = colBase + wc * 64 + n * 16 + (lane & 15);
      const float bb = bias[gcol];
      const int h = gcol >> 6, d = gcol & 63;
      if (z == 0) {
#pragma unroll
        for (int r = 0; r < 4; ++r) {
          const int grow = rowBase + wr * 64 + m * 16 + ((lane >> 4) << 2) + r;
          const int bi = grow >> 11, l = grow & 2047;
          Q[(((size_t)(bi * NHEADS + h)) * LSEQ + l) * DKH + d] =
              f2b((acc[m][n][r] + bb) * scale);
        }
      } else if (z == 1) {
#pragma unroll
        for (int r = 0; r < 4; ++r) {
          const int grow = rowBase + wr * 64 + m * 16 + ((lane >> 4) << 2) + r;
          const int bi = grow >> 11, l = grow & 2047;
          const int bh = bi * NHEADS + h;
          Ksw[(size_t)(bh * 32 + (l >> 6)) * 4096 + ((d >> 3) * 64 + (l & 63)) * 8 + (d & 7)] =
              f2b(acc[m][n][r] + bb);
        }
      } else {
        const int grow0 = rowBase + wr * 64 + m * 16 + ((lane >> 4) << 2);
        const int bi = grow0 >> 11, l0 = grow0 & 2047;
        const int bh = bi * NHEADS + h;
        ushort4 o;
        o.x = f2b(acc[m][n][0] + bb);
        o.y = f2b(acc[m][n][1] + bb);
        o.z = f2b(acc[m][n][2] + bb);
        o.w = f2b(acc[m][n][3] + bb);
        *(ushort4*)(Vsw + (size_t)(bh * 32 + (l0 >> 6)) * 4096 +
                    (((l0 & 63) >> 3) * 64 + d) * 8 + (l0 & 7)) = o;
      }
    }
  }
}

// Flash attention, swapped-QK^T, fixed-max softmax (native v_exp_f32),
// MFMA row-sum, split-K x2, XCD-aware flat grid decode (T1).
// (round-6 structure: LDS double-buffered K/V, best measured = 49.4 us)
__global__ __launch_bounds__(256, 4) void k_attn(
    const unsigned short* __restrict__ Q, const unsigned short* __restrict__ Ksw,
    const unsigned short* __restrict__ Vsw,
    unsigned short* __restrict__ Op0, unsigned short* __restrict__ Op1,
    float* __restrict__ Lp)
{
  __shared__ char Ks[2][8192];   // chunk-major: chunk j at [j*64 + row]*16
  __shared__ char Vs[2][8192];

  const int tid = threadIdx.x, lane = tid & 63, w = tid >> 6;
  const int hi = lane >> 5;
  const int ql = lane & 31;

  const int flat = blockIdx.x;
  const int g  = flat & 63;       // (bh,ks) group -> fixed XCD (flat mod 8)
  const int qi = flat >> 6;       // q-block 0..15
  const int bh = g >> 1, ks = g & 1;
  const int b = bh >> 4, h = bh & 15;
  const int q0 = qi * 128 + w * 32;

  unsigned short* __restrict__ Op = ks ? Op1 : Op0;
  const unsigned short* __restrict__ Qh = Q + (size_t)bh * LSEQ * DKH;

  short8 qf[4];
#pragma unroll
  for (int c = 0; c < 4; ++c)
    qf[c] = *(const short8*)(Qh + (size_t)(q0 + ql) * DKH + c * 16 + hi * 8);

  // ones fragment for the row-sum MFMA
  union { unsigned short u[8]; short8 v; } ones;
#pragma unroll
  for (int j = 0; j < 8; ++j) ones.u[j] = 0x3F80;

  f32x16 oacc[2], lacc, z16;
#pragma unroll
  for (int r = 0; r < 16; ++r) {
    oacc[0][r] = 0.f; oacc[1][r] = 0.f; lacc[r] = 0.f; z16[r] = 0.f;
  }
  float p0 = 0.f;

  auto stage = [&](int buf, int kt2) {
    const unsigned short* Kt = Ksw + (size_t)(bh * 32 + kt2) * 4096;
    const unsigned short* Vt = Vsw + (size_t)(bh * 32 + kt2) * 4096;
#pragma unroll
    for (int p = 0; p < 2; ++p) {
      const int c = p * 256 + tid;
      async16(Kt + c * 8, Ks[buf] + (p * 256 + (tid & 0xC0)) * 16);
      async16(Vt + c * 8, Vs[buf] + (p * 256 + (tid & 0xC0)) * 16);
    }
  };

  const int t0 = ks * (LSEQ / 64 / KSPLIT);
  const int NT = LSEQ / 64 / KSPLIT;

  stage(0, t0);
  __syncthreads();

  int cur = 0;
  for (int it = 0; it < NT; ++it) {
    if (it < NT - 1) stage(cur ^ 1, t0 + it + 1);
    const char* Kc = Ks[cur];
    const char* Vc = Vs[cur];

    // S^T = K Q^T : lane holds S[q=ql][key = b2*32 + (r&3)+8*(r>>2)+4*hi]
    f32x16 sv[2];
#pragma unroll
    for (int b2 = 0; b2 < 2; ++b2) {
      short8 kf = *(const short8*)(Kc + ((0 * 2 + hi) * 64 + b2 * 32 + ql) * 16);
      sv[b2] = __builtin_amdgcn_mfma_f32_32x32x16_bf16(kf, qf[0], z16, 0, 0, 0);
    }
#pragma unroll
    for (int c = 1; c < 4; ++c) {
#pragma unroll
      for (int b2 = 0; b2 < 2; ++b2) {
        short8 kf = *(const short8*)(Kc + ((c * 2 + hi) * 64 + b2 * 32 + ql) * 16);
        sv[b2] = __builtin_amdgcn_mfma_f32_32x32x16_bf16(kf, qf[c], sv[b2], 0, 0, 0);
      }
    }

    // fixed-max softmax numerator: P = exp2(S), native v_exp_f32
#pragma unroll
    for (int b2 = 0; b2 < 2; ++b2)
#pragma unroll
      for (int r = 0; r < 16; ++r) sv[b2][r] = __builtin_amdgcn_exp2f(sv[b2][r]);

    // intervention: halve P for global key 0 (numerator only); save full P0
    if (ks == 0 && it == 0 && hi == 0) { p0 = sv[0][0]; sv[0][0] *= 0.5f; }

    // pack P to bf16 pairs
    unsigned int pk[2][4][2];
#pragma unroll
    for (int b2 = 0; b2 < 2; ++b2)
#pragma unroll
      for (int R = 0; R < 4; ++R) {
        pk[b2][R][0] = cvtpk(sv[b2][4 * R + 0], sv[b2][4 * R + 1]);
        pk[b2][R][1] = cvtpk(sv[b2][4 * R + 2], sv[b2][4 * R + 3]);
      }

    // PV + row-sum via permlane32_swap A-fragments
#pragma unroll
    for (int kc = 0; kc < 4; ++kc) {
      const int b2 = kc >> 1, Rl = 2 * (kc & 1);
      int2v sw0 = pl32swap(pk[b2][Rl][0], pk[b2][Rl + 1][0]);
      int2v sw1 = pl32swap(pk[b2][Rl][1], pk[b2][Rl + 1][1]);
      union { int i[4]; short8 v; } pa;
      pa.i[0] = sw0[0]; pa.i[1] = sw1[0]; pa.i[2] = sw0[1]; pa.i[3] = sw1[1];
      lacc = __builtin_amdgcn_mfma_f32_32x32x16_bf16(pa.v, ones.v, lacc, 0, 0, 0);
#pragma unroll
      for (int n = 0; n < 2; ++n) {
        short8 vb = *(const short8*)(Vc + ((kc * 2 + hi) * 64 + n * 32 + ql) * 16);
        oacc[n] = __builtin_amdgcn_mfma_f32_32x32x16_bf16(pa.v, vb, oacc[n], 0, 0, 0);
      }
    }

    __syncthreads();
    cur ^= 1;
  }

  // epilogue: unnormalized O + per-row l (lacc rows == oacc rows)
#pragma unroll
  for (int r = 0; r < 16; ++r) {
    const int qrow = (r & 3) + 8 * (r >> 2) + 4 * hi;
    float lv = lacc[r];
    if (ks == 0) lv += 0.5f * __shfl(p0, qrow);  // restore full-sum denominator
#pragma unroll
    for (int n = 0; n < 2; ++n) {
      Op[(size_t)(b * LSEQ + q0 + qrow) * DMODEL + h * 64 + n * 32 + ql] =
          f2b(oacc[n][r]);
    }
    if (ql == 0)
      Lp[ks * (32 * LSEQ) + bh * LSEQ + q0 + qrow] = lv;
  }
}

// out = ((O0+O1) * diag(1/(l0+l1))) @ Wo^T + bo, with the split-K combine and
// per-(b,head,q) normalization fused into the A-tile staging. Head == kt
// because the 64-col K-tiles align exactly with heads. A reg-staged (same
// swizzled LDS layout the async16 path produced), B stays global_load_lds.
__global__ __launch_bounds__(256, 2) void k_gemm_out(
    const unsigned short* __restrict__ Op0, const unsigned short* __restrict__ Op1,
    const float* __restrict__ Lp, const unsigned short* __restrict__ Wob,
    const float* __restrict__ bo, float* __restrict__ out)
{
  __shared__ char As[16384];
  __shared__ char Bs[16384];
  const int rowBase = blockIdx.x * 128, colBase = blockIdx.y * 128;
  const int tid  = threadIdx.x;
  const int lane = tid & 63;
  const int wr   = tid >> 7;
  const int wc   = (tid >> 6) & 1;

  f32x4 zero = {0.f, 0.f, 0.f, 0.f};
  f32x4 acc[4][4];
#pragma unroll
  for (int m = 0; m < 4; ++m)
#pragma unroll
    for (int n = 0; n < 4; ++n) acc[m][n] = zero;

  for (int kt = 0; kt < DMODEL / 64; ++kt) {
    const int k0 = kt * 64;
    __syncthreads();
#pragma unroll
    for (int p = 0; p < 4; ++p) {
      const int chunk = p * 256 + tid;
      const int row   = chunk >> 3;
      const int cs    = (chunk & 7) ^ (row & 7);
      const int grow  = rowBase + row;
      // A: fused combine + normalize (head = kt), reg-staged to same layout
      const int bi  = grow >> 11, q = grow & 2047;
      const int bhq = (bi * NHEADS + kt) * LSEQ + q;
      const float invl = 1.0f / (Lp[bhq] + Lp[32 * LSEQ + bhq]);
      const size_t src = (size_t)grow * DMODEL + k0 + cs * 8;
      short8 a0 = *(const short8*)(Op0 + src);
      short8 a1 = *(const short8*)(Op1 + src);
      union { unsigned short u[8]; short8 v; } o;
#pragma unroll
      for (int j = 0; j < 8; ++j)
        o.u[j] = f2b((b2f((unsigned short)a0[j]) + b2f((unsigned short)a1[j])) * invl);
      *(short8*)(As + chunk * 16) = o.v;
      // B: Wo row-panel via async global->LDS
      async16(Wob + (size_t)(colBase + row) * DMODEL + k0 + cs * 8,
              Bs + (p * 256 + (tid & 0xC0)) * 16);
    }
    __syncthreads();
#pragma unroll
    for (int ks = 0; ks < 2; ++ks) {
      short8 af[4], bfr[4];
#pragma unroll
      for (int m = 0; m < 4; ++m) {
        const int ra = wr * 64 + m * 16 + (lane & 15);
        af[m]  = *(const short8*)(As + ra * 128 + (((ks * 4 + (lane >> 4)) ^ (ra & 7)) * 16));
        const int rb = wc * 64 + m * 16 + (lane & 15);
        bfr[m] = *(const short8*)(Bs + rb * 128 + (((ks * 4 + (lane >> 4)) ^ (rb & 7)) * 16));
      }
#pragma unroll
      for (int m = 0; m < 4; ++m)
#pragma unroll
        for (int n = 0; n < 4; ++n)
          acc[m][n] = __builtin_amdgcn_mfma_f32_16x16x32_bf16(af[m], bfr[n], acc[m][n], 0, 0, 0);
    }
  }

#pragma unroll
  for (int m = 0; m < 4; ++m) {
#pragma unroll
    for (int n = 0; n < 4; ++n) {
      const int gcol = colBase + wc * 64 + n * 16 + (lane & 15);
      const float bb = bo[gcol];
#pragma unroll
      for (int r = 0; r < 4; ++r) {
        const int grow = rowBase + wr * 64 + m * 16 + ((lane >> 4) << 2) + r;
        out[(size_t)grow * DMODEL + gcol] = acc[m][n][r] + bb;
      }
    }
  }
}

extern "C" void kernel_launch(void* const* d_in, const int* in_sizes, int n_in,
                              void* d_out, int out_size, void* d_ws, size_t ws_size,
                              hipStream_t stream) {
  const float* x  = (const float*)d_in[0];
  const float* Wq = (const float*)d_in[1];
  const float* bq = (const float*)d_in[2];
  const float* Wk = (const float*)d_in[3];
  const float* bk = (const float*)d_in[4];
  const float* Wv = (const float*)d_in[5];
  const float* bv = (const float*)d_in[6];
  const float* Wo = (const float*)d_in[7];
  const float* bo = (const float*)d_in[8];
  float* out = (float*)d_out;
  char* ws = (char*)d_ws;

  const size_t MB = 1u << 20;
  unsigned short* xb  = (unsigned short*)(ws);             // 8 MB (dead after qkv)
  unsigned short* Wob = (unsigned short*)(ws + 8  * MB);   // 2 MB (live to the end)
  unsigned short* Wqb = (unsigned short*)(ws + 10 * MB);
  unsigned short* Wkb = (unsigned short*)(ws + 12 * MB);
  unsigned short* Wvb = (unsigned short*)(ws + 14 * MB);
  unsigned short* Qb  = (unsigned short*)(ws + 16 * MB);   // 8 MB [bh][l][dk]
  unsigned short* Ksw = (unsigned short*)(ws + 24 * MB);   // 8 MB tiled
  unsigned short* Vsw = (unsigned short*)(ws + 32 * MB);   // 8 MB tiled
  unsigned short* Op0 = (unsigned short*)(ws);             // reuse xb region (8 MB)
  unsigned short* Op1 = (unsigned short*)(ws + 48 * MB);   // 8 MB
  float*          Lpp = (float*)(ws + 56 * MB);            // 512 KB (raw l sums)

  dim3 gcv(1024, 8);
  k_cvtall<<<gcv, 256, 0, stream>>>(x, Wq, Wk, Wv, Wo, xb, Wqb, Wkb, Wvb, Wob);

  dim3 gqkv(MROWS / 128, DMODEL / 128, 3);
  k_gemm_qkv<<<gqkv, 256, 0, stream>>>(xb, Wqb, Wkb, Wvb, bq, bk, bv, Qb, Ksw, Vsw);

  k_attn<<<16 * 32 * KSPLIT, 256, 0, stream>>>(Qb, Ksw, Vsw, Op0, Op1, Lpp);

  dim3 gout(MROWS / 128, DMODEL / 128);
  k_gemm_out<<<gout, 256, 0, stream>>>(Op0, Op1, Lpp, Wob, bo, out);
}

// Round 12
// 124.750 us; speedup vs baseline: 1.0648x; 1.0648x over previous
//
#include <hip/hip_runtime.h>
#include <stdint.h>

#define DMODEL 1024
#define LSEQ   2048
#define NBATCH 2
#define NHEADS 16
#define DKH    64
#define MROWS  4096  // NBATCH*LSEQ
#define KSPLIT 2

typedef __attribute__((ext_vector_type(8))) short short8;
typedef __attribute__((ext_vector_type(4))) float f32x4;
typedef __attribute__((ext_vector_type(16))) float f32x16;
typedef __attribute__((ext_vector_type(2))) int int2v;

__device__ __forceinline__ unsigned short f2b(float f) {
  union { float f; unsigned int u; } v; v.f = f;
  unsigned int r = v.u + 0x7FFFu + ((v.u >> 16) & 1u);
  return (unsigned short)(r >> 16);
}

__device__ __forceinline__ float b2f(unsigned short u) {
  union { unsigned int i; float f; } v; v.i = ((unsigned int)u) << 16; return v.f;
}

__device__ __forceinline__ unsigned int cvtpk(float lo, float hi) {
  unsigned int r;
  asm volatile("v_cvt_pk_bf16_f32 %0, %1, %2" : "=v"(r) : "v"(lo), "v"(hi));
  return r;
}

__device__ __forceinline__ int2v pl32swap(unsigned int a, unsigned int b) {
  return __builtin_amdgcn_permlane32_swap((int)a, (int)b, false, false);
}

__device__ __forceinline__ void async16(const void* g, void* l) {
  __builtin_amdgcn_global_load_lds(
      (const __attribute__((address_space(1))) unsigned int*)g,
      (__attribute__((address_space(3))) unsigned int*)l, 16, 0, 0);
}

// one launch converts x (4 slices) + 4 weight matrices; each slice = 1M floats
__global__ void k_cvtall(const float* __restrict__ x,
                         const float* __restrict__ w0, const float* __restrict__ w1,
                         const float* __restrict__ w2, const float* __restrict__ w3,
                         unsigned short* __restrict__ xb,
                         unsigned short* __restrict__ d0, unsigned short* __restrict__ d1,
                         unsigned short* __restrict__ d2, unsigned short* __restrict__ d3) {
  const int y = blockIdx.y;
  const float* s; unsigned short* d;
  switch (y) {
    case 0: case 1: case 2: case 3:
      s = x + (size_t)y * 1048576; d = xb + (size_t)y * 1048576; break;
    case 4: s = w0; d = d0; break;
    case 5: s = w1; d = d1; break;
    case 6: s = w2; d = d2; break;
    default: s = w3; d = d3; break;
  }
  const int i = blockIdx.x * blockDim.x + threadIdx.x;
  float4 v = ((const float4*)s)[i];
  ushort4 o;
  o.x = f2b(v.x); o.y = f2b(v.y); o.z = f2b(v.z); o.w = f2b(v.w);
  ((ushort4*)d)[i] = o;
}

// acc += A[rowBase:+128, :] @ B[colBase:+128, :]^T  (both row-major [*,1024] bf16)
__device__ __forceinline__ void gemm_mainloop(
    const unsigned short* __restrict__ A, const unsigned short* __restrict__ B,
    int rowBase, int colBase, char* As, char* Bs, f32x4 acc[4][4])
{
  const int tid  = threadIdx.x;
  const int lane = tid & 63;
  const int wr   = tid >> 7;
  const int wc   = (tid >> 6) & 1;
  for (int kt = 0; kt < DMODEL / 64; ++kt) {
    const int k0 = kt * 64;
    __syncthreads();
#pragma unroll
    for (int p = 0; p < 4; ++p) {
      const int chunk = p * 256 + tid;
      const int row   = chunk >> 3;
      const int cs    = (chunk & 7) ^ (row & 7);
      async16(A + (size_t)(rowBase + row) * DMODEL + k0 + cs * 8,
              As + (p * 256 + (tid & 0xC0)) * 16);
      async16(B + (size_t)(colBase + row) * DMODEL + k0 + cs * 8,
              Bs + (p * 256 + (tid & 0xC0)) * 16);
    }
    __syncthreads();
#pragma unroll
    for (int ks = 0; ks < 2; ++ks) {
      short8 af[4], bfr[4];
#pragma unroll
      for (int m = 0; m < 4; ++m) {
        const int ra = wr * 64 + m * 16 + (lane & 15);
        af[m]  = *(const short8*)(As + ra * 128 + (((ks * 4 + (lane >> 4)) ^ (ra & 7)) * 16));
        const int rb = wc * 64 + m * 16 + (lane & 15);
        bfr[m] = *(const short8*)(Bs + rb * 128 + (((ks * 4 + (lane >> 4)) ^ (rb & 7)) * 16));
      }
#pragma unroll
      for (int m = 0; m < 4; ++m)
#pragma unroll
        for (int n = 0; n < 4; ++n)
          acc[m][n] = __builtin_amdgcn_mfma_f32_16x16x32_bf16(af[m], bfr[n], acc[m][n], 0, 0, 0);
    }
  }
}

// z=0: Q (scaled by 0.125*log2e) -> [bh][l][dk] row-major
// z=1: K -> tiled [bh][l/64][dchunk=0..7][row=l&63] 16B chunks
// z=2: V -> tiled [bh][l/64][kchunk=0..7][row=dk]   16B chunks
__global__ __launch_bounds__(256, 2) void k_gemm_qkv(
    const unsigned short* __restrict__ xb,
    const unsigned short* __restrict__ Wqb, const unsigned short* __restrict__ Wkb,
    const unsigned short* __restrict__ Wvb,
    const float* __restrict__ bq, const float* __restrict__ bk, const float* __restrict__ bv,
    unsigned short* __restrict__ Q, unsigned short* __restrict__ Ksw,
    unsigned short* __restrict__ Vsw)
{
  __shared__ char As[16384];
  __shared__ char Bs[16384];
  const int z = blockIdx.z;
  const unsigned short* W = (z == 0) ? Wqb : ((z == 1) ? Wkb : Wvb);
  const float* bias       = (z == 0) ? bq  : ((z == 1) ? bk  : bv);
  const int rowBase = blockIdx.x * 128, colBase = blockIdx.y * 128;

  f32x4 zero = {0.f, 0.f, 0.f, 0.f};
  f32x4 acc[4][4];
#pragma unroll
  for (int m = 0; m < 4; ++m)
#pragma unroll
    for (int n = 0; n < 4; ++n) acc[m][n] = zero;

  gemm_mainloop(xb, W, rowBase, colBase, As, Bs, acc);

  const int tid = threadIdx.x, lane = tid & 63;
  const int wr = tid >> 7, wc = (tid >> 6) & 1;
  const float scale = (z == 0) ? 0.18033688011112042f : 1.0f; // 0.125*log2(e)
#pragma unroll
  for (int m = 0; m < 4; ++m) {
#pragma unroll
    for (int n = 0; n < 4; ++n) {
      const int gcol = colBase + wc * 64 + n * 16 + (lane & 15);
      const float bb = bias[gcol];
      const int h = gcol >> 6, d = gcol & 63;
      if (z == 0) {
#pragma unroll
        for (int r = 0; r < 4; ++r) {
          const int grow = rowBase + wr * 64 + m * 16 + ((lane >> 4) << 2) + r;
          const int bi = grow >> 11, l = grow & 2047;
          Q[(((size_t)(bi * NHEADS + h)) * LSEQ + l) * DKH + d] =
              f2b((acc[m][n][r] + bb) * scale);
        }
      } else if (z == 1) {
#pragma unroll
        for (int r = 0; r < 4; ++r) {
          const int grow = rowBase + wr * 64 + m * 16 + ((lane >> 4) << 2) + r;
          const int bi = grow >> 11, l = grow & 2047;
          const int bh = bi * NHEADS + h;
          Ksw[(size_t)(bh * 32 + (l >> 6)) * 4096 + ((d >> 3) * 64 + (l & 63)) * 8 + (d & 7)] =
              f2b(acc[m][n][r] + bb);
        }
      } else {
        const int grow0 = rowBase + wr * 64 + m * 16 + ((lane >> 4) << 2);
        const int bi = grow0 >> 11, l0 = grow0 & 2047;
        const int bh = bi * NHEADS + h;
        ushort4 o;
        o.x = f2b(acc[m][n][0] + bb);
        o.y = f2b(acc[m][n][1] + bb);
        o.z = f2b(acc[m][n][2] + bb);
        o.w = f2b(acc[m][n][3] + bb);
        *(ushort4*)(Vsw + (size_t)(bh * 32 + (l0 >> 6)) * 4096 +
                    (((l0 & 63) >> 3) * 64 + d) * 8 + (l0 & 7)) = o;
      }
    }
  }
}

// Flash attention, swapped-QK^T, fixed-max softmax (native v_exp_f32),
// MFMA row-sum, split-K x2, XCD-aware flat grid decode (T1).
// (round-6 structure: LDS double-buffered K/V, best measured = 49.4 us)
__global__ __launch_bounds__(256, 4) void k_attn(
    const unsigned short* __restrict__ Q, const unsigned short* __restrict__ Ksw,
    const unsigned short* __restrict__ Vsw,
    unsigned short* __restrict__ Op0, unsigned short* __restrict__ Op1,
    float* __restrict__ Lp)
{
  __shared__ char Ks[2][8192];   // chunk-major: chunk j at [j*64 + row]*16
  __shared__ char Vs[2][8192];

  const int tid = threadIdx.x, lane = tid & 63, w = tid >> 6;
  const int hi = lane >> 5;
  const int ql = lane & 31;

  const int flat = blockIdx.x;
  const int g  = flat & 63;       // (bh,ks) group -> fixed XCD (flat mod 8)
  const int qi = flat >> 6;       // q-block 0..15
  const int bh = g >> 1, ks = g & 1;
  const int b = bh >> 4, h = bh & 15;
  const int q0 = qi * 128 + w * 32;

  unsigned short* __restrict__ Op = ks ? Op1 : Op0;
  const unsigned short* __restrict__ Qh = Q + (size_t)bh * LSEQ * DKH;

  short8 qf[4];
#pragma unroll
  for (int c = 0; c < 4; ++c)
    qf[c] = *(const short8*)(Qh + (size_t)(q0 + ql) * DKH + c * 16 + hi * 8);

  // ones fragment for the row-sum MFMA
  union { unsigned short u[8]; short8 v; } ones;
#pragma unroll
  for (int j = 0; j < 8; ++j) ones.u[j] = 0x3F80;

  f32x16 oacc[2], lacc, z16;
#pragma unroll
  for (int r = 0; r < 16; ++r) {
    oacc[0][r] = 0.f; oacc[1][r] = 0.f; lacc[r] = 0.f; z16[r] = 0.f;
  }
  float p0 = 0.f;

  auto stage = [&](int buf, int kt2) {
    const unsigned short* Kt = Ksw + (size_t)(bh * 32 + kt2) * 4096;
    const unsigned short* Vt = Vsw + (size_t)(bh * 32 + kt2) * 4096;
#pragma unroll
    for (int p = 0; p < 2; ++p) {
      const int c = p * 256 + tid;
      async16(Kt + c * 8, Ks[buf] + (p * 256 + (tid & 0xC0)) * 16);
      async16(Vt + c * 8, Vs[buf] + (p * 256 + (tid & 0xC0)) * 16);
    }
  };

  const int t0 = ks * (LSEQ / 64 / KSPLIT);
  const int NT = LSEQ / 64 / KSPLIT;

  stage(0, t0);
  __syncthreads();

  int cur = 0;
  for (int it = 0; it < NT; ++it) {
    if (it < NT - 1) stage(cur ^ 1, t0 + it + 1);
    const char* Kc = Ks[cur];
    const char* Vc = Vs[cur];

    // S^T = K Q^T : lane holds S[q=ql][key = b2*32 + (r&3)+8*(r>>2)+4*hi]
    f32x16 sv[2];
#pragma unroll
    for (int b2 = 0; b2 < 2; ++b2) {
      short8 kf = *(const short8*)(Kc + ((0 * 2 + hi) * 64 + b2 * 32 + ql) * 16);
      sv[b2] = __builtin_amdgcn_mfma_f32_32x32x16_bf16(kf, qf[0], z16, 0, 0, 0);
    }
#pragma unroll
    for (int c = 1; c < 4; ++c) {
#pragma unroll
      for (int b2 = 0; b2 < 2; ++b2) {
        short8 kf = *(const short8*)(Kc + ((c * 2 + hi) * 64 + b2 * 32 + ql) * 16);
        sv[b2] = __builtin_amdgcn_mfma_f32_32x32x16_bf16(kf, qf[c], sv[b2], 0, 0, 0);
      }
    }

    // fixed-max softmax numerator: P = exp2(S), native v_exp_f32
#pragma unroll
    for (int b2 = 0; b2 < 2; ++b2)
#pragma unroll
      for (int r = 0; r < 16; ++r) sv[b2][r] = __builtin_amdgcn_exp2f(sv[b2][r]);

    // intervention: halve P for global key 0 (numerator only); save full P0
    if (ks == 0 && it == 0 && hi == 0) { p0 = sv[0][0]; sv[0][0] *= 0.5f; }

    // pack P to bf16 pairs
    unsigned int pk[2][4][2];
#pragma unroll
    for (int b2 = 0; b2 < 2; ++b2)
#pragma unroll
      for (int R = 0; R < 4; ++R) {
        pk[b2][R][0] = cvtpk(sv[b2][4 * R + 0], sv[b2][4 * R + 1]);
        pk[b2][R][1] = cvtpk(sv[b2][4 * R + 2], sv[b2][4 * R + 3]);
      }

    // PV + row-sum via permlane32_swap A-fragments
#pragma unroll
    for (int kc = 0; kc < 4; ++kc) {
      const int b2 = kc >> 1, Rl = 2 * (kc & 1);
      int2v sw0 = pl32swap(pk[b2][Rl][0], pk[b2][Rl + 1][0]);
      int2v sw1 = pl32swap(pk[b2][Rl][1], pk[b2][Rl + 1][1]);
      union { int i[4]; short8 v; } pa;
      pa.i[0] = sw0[0]; pa.i[1] = sw1[0]; pa.i[2] = sw0[1]; pa.i[3] = sw1[1];
      lacc = __builtin_amdgcn_mfma_f32_32x32x16_bf16(pa.v, ones.v, lacc, 0, 0, 0);
#pragma unroll
      for (int n = 0; n < 2; ++n) {
        short8 vb = *(const short8*)(Vc + ((kc * 2 + hi) * 64 + n * 32 + ql) * 16);
        oacc[n] = __builtin_amdgcn_mfma_f32_32x32x16_bf16(pa.v, vb, oacc[n], 0, 0, 0);
      }
    }

    __syncthreads();
    cur ^= 1;
  }

  // epilogue: unnormalized O + per-row l (lacc rows == oacc rows)
#pragma unroll
  for (int r = 0; r < 16; ++r) {
    const int qrow = (r & 3) + 8 * (r >> 2) + 4 * hi;
    float lv = lacc[r];
    if (ks == 0) lv += 0.5f * __shfl(p0, qrow);  // restore full-sum denominator
#pragma unroll
    for (int n = 0; n < 2; ++n) {
      Op[(size_t)(b * LSEQ + q0 + qrow) * DMODEL + h * 64 + n * 32 + ql] =
          f2b(oacc[n][r]);
    }
    if (ql == 0)
      Lp[ks * (32 * LSEQ) + bh * LSEQ + q0 + qrow] = lv;
  }
}

// out = ((O0+O1) * diag(1/(l0+l1))) @ Wo^T + bo. Split-K combine + normalize
// fused into A staging, SOFTWARE-PIPELINED one K-step ahead: loads for kt+1
// are issued AFTER the second barrier (so the barrier's vmcnt(0) drain cannot
// kill them) and age across the MFMA phase; the combine at the top of the next
// iteration finds them (mostly) complete. Head == kt (64-col K-tiles == heads).
__global__ __launch_bounds__(256, 2) void k_gemm_out(
    const unsigned short* __restrict__ Op0, const unsigned short* __restrict__ Op1,
    const float* __restrict__ Lp, const unsigned short* __restrict__ Wob,
    const float* __restrict__ bo, float* __restrict__ out)
{
  __shared__ char As[16384];
  __shared__ char Bs[16384];
  const int rowBase = blockIdx.x * 128, colBase = blockIdx.y * 128;
  const int tid  = threadIdx.x;
  const int lane = tid & 63;
  const int wr   = tid >> 7;
  const int wc   = (tid >> 6) & 1;

  f32x4 zero = {0.f, 0.f, 0.f, 0.f};
  f32x4 acc[4][4];
#pragma unroll
  for (int m = 0; m < 4; ++m)
#pragma unroll
    for (int n = 0; n < 4; ++n) acc[m][n] = zero;

  // per-p invariants
  int rowp[4], csp[4], bhq0[4];
  size_t srcb[4];
#pragma unroll
  for (int p = 0; p < 4; ++p) {
    const int chunk = p * 256 + tid;
    const int row = chunk >> 3;
    const int cs  = (chunk & 7) ^ (row & 7);
    const int grow = rowBase + row;
    rowp[p] = row; csp[p] = cs;
    srcb[p] = (size_t)grow * DMODEL + cs * 8;
    bhq0[p] = ((grow >> 11) * NHEADS) * LSEQ + (grow & 2047);  // + kt*LSEQ
  }

  short8 a0r[4], a1r[4];
  float ls[4];
  // prologue: issue loads for kt = 0
#pragma unroll
  for (int p = 0; p < 4; ++p) {
    a0r[p] = *(const short8*)(Op0 + srcb[p]);
    a1r[p] = *(const short8*)(Op1 + srcb[p]);
    ls[p]  = Lp[bhq0[p]] + Lp[32 * LSEQ + bhq0[p]];
  }

  for (int kt = 0; kt < DMODEL / 64; ++kt) {
    // combine(kt) in registers (loads issued last iteration; wait is hidden)
    union { unsigned short u[8]; short8 v; } st[4];
#pragma unroll
    for (int p = 0; p < 4; ++p) {
      const float invl = 1.0f / ls[p];
#pragma unroll
      for (int j = 0; j < 8; ++j)
        st[p].u[j] = f2b((b2f((unsigned short)a0r[p][j]) +
                          b2f((unsigned short)a1r[p][j])) * invl);
    }
    __syncthreads();   // previous MFMA phase done reading As/Bs
#pragma unroll
    for (int p = 0; p < 4; ++p) {
      *(short8*)(As + (p * 256 + tid) * 16) = st[p].v;
      async16(Wob + (size_t)(colBase + rowp[p]) * DMODEL + kt * 64 + csp[p] * 8,
              Bs + (p * 256 + (tid & 0xC0)) * 16);
    }
    __syncthreads();   // staging visible (drains ds_write + async16 only)

    // prefetch kt+1 AFTER the barrier so it survives; ages across MFMA phase
    if (kt < DMODEL / 64 - 1) {
#pragma unroll
      for (int p = 0; p < 4; ++p) {
        const size_t src = srcb[p] + (kt + 1) * 64;
        a0r[p] = *(const short8*)(Op0 + src);
        a1r[p] = *(const short8*)(Op1 + src);
        const int bhq = bhq0[p] + (kt + 1) * LSEQ;
        ls[p] = Lp[bhq] + Lp[32 * LSEQ + bhq];
      }
    }

#pragma unroll
    for (int ks = 0; ks < 2; ++ks) {
      short8 af[4], bfr[4];
#pragma unroll
      for (int m = 0; m < 4; ++m) {
        const int ra = wr * 64 + m * 16 + (lane & 15);
        af[m]  = *(const short8*)(As + ra * 128 + (((ks * 4 + (lane >> 4)) ^ (ra & 7)) * 16));
        const int rb = wc * 64 + m * 16 + (lane & 15);
        bfr[m] = *(const short8*)(Bs + rb * 128 + (((ks * 4 + (lane >> 4)) ^ (rb & 7)) * 16));
      }
#pragma unroll
      for (int m = 0; m < 4; ++m)
#pragma unroll
        for (int n = 0; n < 4; ++n)
          acc[m][n] = __builtin_amdgcn_mfma_f32_16x16x32_bf16(af[m], bfr[n], acc[m][n], 0, 0, 0);
    }
  }

#pragma unroll
  for (int m = 0; m < 4; ++m) {
#pragma unroll
    for (int n = 0; n < 4; ++n) {
      const int gcol = colBase + wc * 64 + n * 16 + (lane & 15);
      const float bb = bo[gcol];
#pragma unroll
      for (int r = 0; r < 4; ++r) {
        const int grow = rowBase + wr * 64 + m * 16 + ((lane >> 4) << 2) + r;
        out[(size_t)grow * DMODEL + gcol] = acc[m][n][r] + bb;
      }
    }
  }
}

extern "C" void kernel_launch(void* const* d_in, const int* in_sizes, int n_in,
                              void* d_out, int out_size, void* d_ws, size_t ws_size,
                              hipStream_t stream) {
  const float* x  = (const float*)d_in[0];
  const float* Wq = (const float*)d_in[1];
  const float* bq = (const float*)d_in[2];
  const float* Wk = (const float*)d_in[3];
  const float* bk = (const float*)d_in[4];
  const float* Wv = (const float*)d_in[5];
  const float* bv = (const float*)d_in[6];
  const float* Wo = (const float*)d_in[7];
  const float* bo = (const float*)d_in[8];
  float* out = (float*)d_out;
  char* ws = (char*)d_ws;

  const size_t MB = 1u << 20;
  unsigned short* xb  = (unsigned short*)(ws);             // 8 MB (dead after qkv)
  unsigned short* Wob = (unsigned short*)(ws + 8  * MB);   // 2 MB (live to the end)
  unsigned short* Wqb = (unsigned short*)(ws + 10 * MB);
  unsigned short* Wkb = (unsigned short*)(ws + 12 * MB);
  unsigned short* Wvb = (unsigned short*)(ws + 14 * MB);
  unsigned short* Qb  = (unsigned short*)(ws + 16 * MB);   // 8 MB [bh][l][dk]
  unsigned short* Ksw = (unsigned short*)(ws + 24 * MB);   // 8 MB tiled
  unsigned short* Vsw = (unsigned short*)(ws + 32 * MB);   // 8 MB tiled
  unsigned short* Op0 = (unsigned short*)(ws);             // reuse xb region (8 MB)
  unsigned short* Op1 = (unsigned short*)(ws + 48 * MB);   // 8 MB
  float*          Lpp = (float*)(ws + 56 * MB);            // 512 KB (raw l sums)

  dim3 gcv(1024, 8);
  k_cvtall<<<gcv, 256, 0, stream>>>(x, Wq, Wk, Wv, Wo, xb, Wqb, Wkb, Wvb, Wob);

  dim3 gqkv(MROWS / 128, DMODEL / 128, 3);
  k_gemm_qkv<<<gqkv, 256, 0, stream>>>(xb, Wqb, Wkb, Wvb, bq, bk, bv, Qb, Ksw, Vsw);

  k_attn<<<16 * 32 * KSPLIT, 256, 0, stream>>>(Qb, Ksw, Vsw, Op0, Op1, Lpp);

  dim3 gout(MROWS / 128, DMODEL / 128);
  k_gemm_out<<<gout, 256, 0, stream>>>(Op0, Op1, Lpp, Wob, bo, out);
}

// Round 13
// 121.420 us; speedup vs baseline: 1.0940x; 1.0274x over previous
//
#include <hip/hip_runtime.h>
#include <stdint.h>

#define DMODEL 1024
#define LSEQ   2048
#define NBATCH 2
#define NHEADS 16
#define DKH    64
#define MROWS  4096  // NBATCH*LSEQ

typedef __attribute__((ext_vector_type(8))) short short8;
typedef __attribute__((ext_vector_type(4))) float f32x4;
typedef __attribute__((ext_vector_type(16))) float f32x16;
typedef __attribute__((ext_vector_type(2))) int int2v;

__device__ __forceinline__ unsigned short f2b(float f) {
  union { float f; unsigned int u; } v; v.f = f;
  unsigned int r = v.u + 0x7FFFu + ((v.u >> 16) & 1u);
  return (unsigned short)(r >> 16);
}

__device__ __forceinline__ float b2f(unsigned short u) {
  union { unsigned int i; float f; } v; v.i = ((unsigned int)u) << 16; return v.f;
}

__device__ __forceinline__ unsigned int cvtpk(float lo, float hi) {
  unsigned int r;
  asm volatile("v_cvt_pk_bf16_f32 %0, %1, %2" : "=v"(r) : "v"(lo), "v"(hi));
  return r;
}

__device__ __forceinline__ int2v pl32swap(unsigned int a, unsigned int b) {
  return __builtin_amdgcn_permlane32_swap((int)a, (int)b, false, false);
}

__device__ __forceinline__ void async16(const void* g, void* l) {
  __builtin_amdgcn_global_load_lds(
      (const __attribute__((address_space(1))) unsigned int*)g,
      (__attribute__((address_space(3))) unsigned int*)l, 16, 0, 0);
}

// one launch converts x (4 slices) + 4 weight matrices; each slice = 1M floats
__global__ void k_cvtall(const float* __restrict__ x,
                         const float* __restrict__ w0, const float* __restrict__ w1,
                         const float* __restrict__ w2, const float* __restrict__ w3,
                         unsigned short* __restrict__ xb,
                         unsigned short* __restrict__ d0, unsigned short* __restrict__ d1,
                         unsigned short* __restrict__ d2, unsigned short* __restrict__ d3) {
  const int y = blockIdx.y;
  const float* s; unsigned short* d;
  switch (y) {
    case 0: case 1: case 2: case 3:
      s = x + (size_t)y * 1048576; d = xb + (size_t)y * 1048576; break;
    case 4: s = w0; d = d0; break;
    case 5: s = w1; d = d1; break;
    case 6: s = w2; d = d2; break;
    default: s = w3; d = d3; break;
  }
  const int i = blockIdx.x * blockDim.x + threadIdx.x;
  float4 v = ((const float4*)s)[i];
  ushort4 o;
  o.x = f2b(v.x); o.y = f2b(v.y); o.z = f2b(v.z); o.w = f2b(v.w);
  ((ushort4*)d)[i] = o;
}

// acc += A[rowBase:+128, :] @ B[colBase:+128, :]^T  (both row-major [*,1024] bf16)
__device__ __forceinline__ void gemm_mainloop(
    const unsigned short* __restrict__ A, const unsigned short* __restrict__ B,
    int rowBase, int colBase, char* As, char* Bs, f32x4 acc[4][4])
{
  const int tid  = threadIdx.x;
  const int lane = tid & 63;
  const int wr   = tid >> 7;
  const int wc   = (tid >> 6) & 1;
  for (int kt = 0; kt < DMODEL / 64; ++kt) {
    const int k0 = kt * 64;
    __syncthreads();
#pragma unroll
    for (int p = 0; p < 4; ++p) {
      const int chunk = p * 256 + tid;
      const int row   = chunk >> 3;
      const int cs    = (chunk & 7) ^ (row & 7);
      async16(A + (size_t)(rowBase + row) * DMODEL + k0 + cs * 8,
              As + (p * 256 + (tid & 0xC0)) * 16);
      async16(B + (size_t)(colBase + row) * DMODEL + k0 + cs * 8,
              Bs + (p * 256 + (tid & 0xC0)) * 16);
    }
    __syncthreads();
#pragma unroll
    for (int ks = 0; ks < 2; ++ks) {
      short8 af[4], bfr[4];
#pragma unroll
      for (int m = 0; m < 4; ++m) {
        const int ra = wr * 64 + m * 16 + (lane & 15);
        af[m]  = *(const short8*)(As + ra * 128 + (((ks * 4 + (lane >> 4)) ^ (ra & 7)) * 16));
        const int rb = wc * 64 + m * 16 + (lane & 15);
        bfr[m] = *(const short8*)(Bs + rb * 128 + (((ks * 4 + (lane >> 4)) ^ (rb & 7)) * 16));
      }
#pragma unroll
      for (int m = 0; m < 4; ++m)
#pragma unroll
        for (int n = 0; n < 4; ++n)
          acc[m][n] = __builtin_amdgcn_mfma_f32_16x16x32_bf16(af[m], bfr[n], acc[m][n], 0, 0, 0);
    }
  }
}

// z=0: Q (scaled by 0.125*log2e) -> [bh][l][dk] row-major
// z=1: K -> tiled [bh][l/64][dchunk=0..7][row=l&63] 16B chunks
// z=2: V -> tiled [bh][l/64][kchunk=0..7][row=dk]   16B chunks
__global__ __launch_bounds__(256, 2) void k_gemm_qkv(
    const unsigned short* __restrict__ xb,
    const unsigned short* __restrict__ Wqb, const unsigned short* __restrict__ Wkb,
    const unsigned short* __restrict__ Wvb,
    const float* __restrict__ bq, const float* __restrict__ bk, const float* __restrict__ bv,
    unsigned short* __restrict__ Q, unsigned short* __restrict__ Ksw,
    unsigned short* __restrict__ Vsw)
{
  __shared__ char As[16384];
  __shared__ char Bs[16384];
  const int z = blockIdx.z;
  const unsigned short* W = (z == 0) ? Wqb : ((z == 1) ? Wkb : Wvb);
  const float* bias       = (z == 0) ? bq  : ((z == 1) ? bk  : bv);
  const int rowBase = blockIdx.x * 128, colBase = blockIdx.y * 128;

  f32x4 zero = {0.f, 0.f, 0.f, 0.f};
  f32x4 acc[4][4];
#pragma unroll
  for (int m = 0; m < 4; ++m)
#pragma unroll
    for (int n = 0; n < 4; ++n) acc[m][n] = zero;

  gemm_mainloop(xb, W, rowBase, colBase, As, Bs, acc);

  const int tid = threadIdx.x, lane = tid & 63;
  const int wr = tid >> 7, wc = (tid >> 6) & 1;
  const float scale = (z == 0) ? 0.18033688011112042f : 1.0f; // 0.125*log2(e)
#pragma unroll
  for (int m = 0; m < 4; ++m) {
#pragma unroll
    for (int n = 0; n < 4; ++n) {
      const int gcol = colBase + wc * 64 + n * 16 + (lane & 15);
      const float bb = bias[gcol];
      const int h = gcol >> 6, d = gcol & 63;
      if (z == 0) {
#pragma unroll
        for (int r = 0; r < 4; ++r) {
          const int grow = rowBase + wr * 64 + m * 16 + ((lane >> 4) << 2) + r;
          const int bi = grow >> 11, l = grow & 2047;
          Q[(((size_t)(bi * NHEADS + h)) * LSEQ + l) * DKH + d] =
              f2b((acc[m][n][r] + bb) * scale);
        }
      } else if (z == 1) {
#pragma unroll
        for (int r = 0; r < 4; ++r) {
          const int grow = rowBase + wr * 64 + m * 16 + ((lane >> 4) << 2) + r;
          const int bi = grow >> 11, l = grow & 2047;
          const int bh = bi * NHEADS + h;
          Ksw[(size_t)(bh * 32 + (l >> 6)) * 4096 + ((d >> 3) * 64 + (l & 63)) * 8 + (d & 7)] =
              f2b(acc[m][n][r] + bb);
        }
      } else {
        const int grow0 = rowBase + wr * 64 + m * 16 + ((lane >> 4) << 2);
        const int bi = grow0 >> 11, l0 = grow0 & 2047;
        const int bh = bi * NHEADS + h;
        ushort4 o;
        o.x = f2b(acc[m][n][0] + bb);
        o.y = f2b(acc[m][n][1] + bb);
        o.z = f2b(acc[m][n][2] + bb);
        o.w = f2b(acc[m][n][3] + bb);
        *(ushort4*)(Vsw + (size_t)(bh * 32 + (l0 >> 6)) * 4096 +
                    (((l0 & 63) >> 3) * 64 + d) * 8 + (l0 & 7)) = o;
      }
    }
  }
}

// Flash attention, swapped-QK^T, fixed-max softmax (native v_exp_f32),
// MFMA row-sum, split-K x NSPLIT, XCD-aware flat grid decode (T1).
// r6 structure (proven 49.4 us at NSPLIT=2); NSPLIT=4 doubles resident blocks
// (2048 blocks, LDS-capped 5/CU = 20 waves/CU) to attack the TLP deficit.
template <int NSPLIT>
__global__ __launch_bounds__(256, 4) void k_attn(
    const unsigned short* __restrict__ Q, const unsigned short* __restrict__ Ksw,
    const unsigned short* __restrict__ Vsw,
    unsigned short* __restrict__ O0, unsigned short* __restrict__ O1,
    unsigned short* __restrict__ O2, unsigned short* __restrict__ O3,
    float* __restrict__ Lp)
{
  __shared__ char Ks[2][8192];   // chunk-major: chunk j at [j*64 + row]*16
  __shared__ char Vs[2][8192];

  const int tid = threadIdx.x, lane = tid & 63, w = tid >> 6;
  const int hi = lane >> 5;
  const int ql = lane & 31;

  const int GROUPS = 32 * NSPLIT;          // 64 or 128, both % 8 == 0
  const int flat = blockIdx.x;
  const int g  = flat & (GROUPS - 1);      // (bh,ks) group -> fixed XCD (flat%8)
  const int qi = flat / GROUPS;            // q-block 0..15
  const int bh = g / NSPLIT, ks = g & (NSPLIT - 1);
  const int b = bh >> 4, h = bh & 15;
  const int q0 = qi * 128 + w * 32;

  unsigned short* __restrict__ Op =
      (ks == 0) ? O0 : ((ks == 1) ? O1 : ((ks == 2) ? O2 : O3));
  const unsigned short* __restrict__ Qh = Q + (size_t)bh * LSEQ * DKH;

  short8 qf[4];
#pragma unroll
  for (int c = 0; c < 4; ++c)
    qf[c] = *(const short8*)(Qh + (size_t)(q0 + ql) * DKH + c * 16 + hi * 8);

  union { unsigned short u[8]; short8 v; } ones;
#pragma unroll
  for (int j = 0; j < 8; ++j) ones.u[j] = 0x3F80;

  f32x16 oacc[2], lacc, z16;
#pragma unroll
  for (int r = 0; r < 16; ++r) {
    oacc[0][r] = 0.f; oacc[1][r] = 0.f; lacc[r] = 0.f; z16[r] = 0.f;
  }
  float p0 = 0.f;

  auto stage = [&](int buf, int kt2) {
    const unsigned short* Kt = Ksw + (size_t)(bh * 32 + kt2) * 4096;
    const unsigned short* Vt = Vsw + (size_t)(bh * 32 + kt2) * 4096;
#pragma unroll
    for (int p = 0; p < 2; ++p) {
      const int c = p * 256 + tid;
      async16(Kt + c * 8, Ks[buf] + (p * 256 + (tid & 0xC0)) * 16);
      async16(Vt + c * 8, Vs[buf] + (p * 256 + (tid & 0xC0)) * 16);
    }
  };

  const int NT = 32 / NSPLIT;
  const int t0 = ks * NT;

  stage(0, t0);
  __syncthreads();

  int cur = 0;
  for (int it = 0; it < NT; ++it) {
    if (it < NT - 1) stage(cur ^ 1, t0 + it + 1);
    const char* Kc = Ks[cur];
    const char* Vc = Vs[cur];

    // S^T = K Q^T : lane holds S[q=ql][key = b2*32 + (r&3)+8*(r>>2)+4*hi]
    f32x16 sv[2];
#pragma unroll
    for (int b2 = 0; b2 < 2; ++b2) {
      short8 kf = *(const short8*)(Kc + ((0 * 2 + hi) * 64 + b2 * 32 + ql) * 16);
      sv[b2] = __builtin_amdgcn_mfma_f32_32x32x16_bf16(kf, qf[0], z16, 0, 0, 0);
    }
#pragma unroll
    for (int c = 1; c < 4; ++c) {
#pragma unroll
      for (int b2 = 0; b2 < 2; ++b2) {
        short8 kf = *(const short8*)(Kc + ((c * 2 + hi) * 64 + b2 * 32 + ql) * 16);
        sv[b2] = __builtin_amdgcn_mfma_f32_32x32x16_bf16(kf, qf[c], sv[b2], 0, 0, 0);
      }
    }

    // fixed-max softmax numerator: P = exp2(S), native v_exp_f32
#pragma unroll
    for (int b2 = 0; b2 < 2; ++b2)
#pragma unroll
      for (int r = 0; r < 16; ++r) sv[b2][r] = __builtin_amdgcn_exp2f(sv[b2][r]);

    // intervention: halve P for global key 0 (numerator only); save full P0
    if (ks == 0 && it == 0 && hi == 0) { p0 = sv[0][0]; sv[0][0] *= 0.5f; }

    // pack P to bf16 pairs
    unsigned int pk[2][4][2];
#pragma unroll
    for (int b2 = 0; b2 < 2; ++b2)
#pragma unroll
      for (int R = 0; R < 4; ++R) {
        pk[b2][R][0] = cvtpk(sv[b2][4 * R + 0], sv[b2][4 * R + 1]);
        pk[b2][R][1] = cvtpk(sv[b2][4 * R + 2], sv[b2][4 * R + 3]);
      }

    // PV + row-sum via permlane32_swap A-fragments
#pragma unroll
    for (int kc = 0; kc < 4; ++kc) {
      const int b2 = kc >> 1, Rl = 2 * (kc & 1);
      int2v sw0 = pl32swap(pk[b2][Rl][0], pk[b2][Rl + 1][0]);
      int2v sw1 = pl32swap(pk[b2][Rl][1], pk[b2][Rl + 1][1]);
      union { int i[4]; short8 v; } pa;
      pa.i[0] = sw0[0]; pa.i[1] = sw1[0]; pa.i[2] = sw0[1]; pa.i[3] = sw1[1];
      lacc = __builtin_amdgcn_mfma_f32_32x32x16_bf16(pa.v, ones.v, lacc, 0, 0, 0);
#pragma unroll
      for (int n = 0; n < 2; ++n) {
        short8 vb = *(const short8*)(Vc + ((kc * 2 + hi) * 64 + n * 32 + ql) * 16);
        oacc[n] = __builtin_amdgcn_mfma_f32_32x32x16_bf16(pa.v, vb, oacc[n], 0, 0, 0);
      }
    }

    __syncthreads();
    cur ^= 1;
  }

  // epilogue: unnormalized O + per-row l (lacc rows == oacc rows)
#pragma unroll
  for (int r = 0; r < 16; ++r) {
    const int qrow = (r & 3) + 8 * (r >> 2) + 4 * hi;
    float lv = lacc[r];
    if (ks == 0) lv += 0.5f * __shfl(p0, qrow);  // restore full-sum denominator
#pragma unroll
    for (int n = 0; n < 2; ++n) {
      Op[(size_t)(b * LSEQ + q0 + qrow) * DMODEL + h * 64 + n * 32 + ql] =
          f2b(oacc[n][r]);
    }
    if (ql == 0)
      Lp[ks * (32 * LSEQ) + bh * LSEQ + q0 + qrow] = lv;
  }
}

// AO = (sum of partials) / (sum of l)
template <int NSPLIT>
__global__ void k_combine(const unsigned short* __restrict__ o0,
                          const unsigned short* __restrict__ o1,
                          const unsigned short* __restrict__ o2,
                          const unsigned short* __restrict__ o3,
                          const float* __restrict__ Lp,
                          unsigned short* __restrict__ AO)
{
  const int i = blockIdx.x * blockDim.x + threadIdx.x;  // short8 index (524288)
  const int row = i >> 7;
  const int q = row & 2047, b = row >> 11;
  const int h = (i & 127) >> 3;
  const int bhq = (b * 16 + h) * 2048 + q;
  float ltot = Lp[bhq] + Lp[32 * LSEQ + bhq];
  if (NSPLIT == 4) ltot += Lp[2 * 32 * LSEQ + bhq] + Lp[3 * 32 * LSEQ + bhq];
  const float inv = 1.0f / ltot;
  short8 a = ((const short8*)o0)[i];
  short8 c = ((const short8*)o1)[i];
  union { unsigned short u[8]; short8 v; } o;
  if (NSPLIT == 2) {
#pragma unroll
    for (int j = 0; j < 8; ++j)
      o.u[j] = f2b((b2f((unsigned short)a[j]) + b2f((unsigned short)c[j])) * inv);
  } else {
    short8 d = ((const short8*)o2)[i];
    short8 e = ((const short8*)o3)[i];
#pragma unroll
    for (int j = 0; j < 8; ++j)
      o.u[j] = f2b((b2f((unsigned short)a[j]) + b2f((unsigned short)c[j]) +
                    b2f((unsigned short)d[j]) + b2f((unsigned short)e[j])) * inv);
  }
  ((short8*)AO)[i] = o.v;
}

__global__ __launch_bounds__(256, 2) void k_gemm_out(
    const unsigned short* __restrict__ AO, const unsigned short* __restrict__ Wob,
    const float* __restrict__ bo, float* __restrict__ out)
{
  __shared__ char As[16384];
  __shared__ char Bs[16384];
  const int rowBase = blockIdx.x * 128, colBase = blockIdx.y * 128;
  f32x4 zero = {0.f, 0.f, 0.f, 0.f};
  f32x4 acc[4][4];
#pragma unroll
  for (int m = 0; m < 4; ++m)
#pragma unroll
    for (int n = 0; n < 4; ++n) acc[m][n] = zero;

  gemm_mainloop(AO, Wob, rowBase, colBase, As, Bs, acc);

  const int tid = threadIdx.x, lane = tid & 63;
  const int wr = tid >> 7, wc = (tid >> 6) & 1;
#pragma unroll
  for (int m = 0; m < 4; ++m) {
#pragma unroll
    for (int n = 0; n < 4; ++n) {
      const int gcol = colBase + wc * 64 + n * 16 + (lane & 15);
      const float bb = bo[gcol];
#pragma unroll
      for (int r = 0; r < 4; ++r) {
        const int grow = rowBase + wr * 64 + m * 16 + ((lane >> 4) << 2) + r;
        out[(size_t)grow * DMODEL + gcol] = acc[m][n][r] + bb;
      }
    }
  }
}

extern "C" void kernel_launch(void* const* d_in, const int* in_sizes, int n_in,
                              void* d_out, int out_size, void* d_ws, size_t ws_size,
                              hipStream_t stream) {
  const float* x  = (const float*)d_in[0];
  const float* Wq = (const float*)d_in[1];
  const float* bq = (const float*)d_in[2];
  const float* Wk = (const float*)d_in[3];
  const float* bk = (const float*)d_in[4];
  const float* Wv = (const float*)d_in[5];
  const float* bv = (const float*)d_in[6];
  const float* Wo = (const float*)d_in[7];
  const float* bo = (const float*)d_in[8];
  float* out = (float*)d_out;
  char* ws = (char*)d_ws;

  const size_t MB = 1u << 20;
  unsigned short* xb  = (unsigned short*)(ws);             // 0-8  (dead after qkv)
  unsigned short* Wob = (unsigned short*)(ws + 8  * MB);   // 8-10 (live to end)
  float*          Lpp = (float*)(ws + 10 * MB);            // 10-11 (attn phase; Wqb slot)
  unsigned short* Wqb = (unsigned short*)(ws + 10 * MB);   // 10-12 (qkv phase)
  unsigned short* Wkb = (unsigned short*)(ws + 12 * MB);
  unsigned short* Wvb = (unsigned short*)(ws + 14 * MB);
  unsigned short* Qb  = (unsigned short*)(ws + 16 * MB);   // 16-24 (dead after attn)
  unsigned short* AOb = (unsigned short*)(ws + 16 * MB);   // reuse Qb slot post-attn
  unsigned short* Ksw = (unsigned short*)(ws + 24 * MB);   // 24-32
  unsigned short* Vsw = (unsigned short*)(ws + 32 * MB);   // 32-40
  unsigned short* Op0 = (unsigned short*)(ws);             // reuse xb slot
  unsigned short* Op1 = (unsigned short*)(ws + 40 * MB);   // 40-48
  unsigned short* Op2 = (unsigned short*)(ws + 48 * MB);   // 48-56 (KSPLIT4)
  unsigned short* Op3 = (unsigned short*)(ws + 56 * MB);   // 56-64 (KSPLIT4)

  // NOTE: Lpp overlaps Wqb — temporally disjoint (Lpp written during attn,
  // after qkv has consumed Wqb).

  dim3 gcv(1024, 8);
  k_cvtall<<<gcv, 256, 0, stream>>>(x, Wq, Wk, Wv, Wo, xb, Wqb, Wkb, Wvb, Wob);

  dim3 gqkv(MROWS / 128, DMODEL / 128, 3);
  k_gemm_qkv<<<gqkv, 256, 0, stream>>>(xb, Wqb, Wkb, Wvb, bq, bk, bv, Qb, Ksw, Vsw);

  const bool big = ws_size >= 64 * MB;   // deterministic: ws_size fixed per run
  if (big) {
    k_attn<4><<<16 * 32 * 4, 256, 0, stream>>>(Qb, Ksw, Vsw, Op0, Op1, Op2, Op3, Lpp);
    k_combine<4><<<2048, 256, 0, stream>>>(Op0, Op1, Op2, Op3, Lpp, AOb);
  } else {
    k_attn<2><<<16 * 32 * 2, 256, 0, stream>>>(Qb, Ksw, Vsw, Op0, Op1, Op1, Op1, Lpp);
    k_combine<2><<<2048, 256, 0, stream>>>(Op0, Op1, Op1, Op1, Lpp, AOb);
  }

  dim3 gout(MROWS / 128, DMODEL / 128);
  k_gemm_out<<<gout, 256, 0, stream>>>(AOb, Wob, bo, out);
}

// Round 14
// 109.828 us; speedup vs baseline: 1.2094x; 1.1055x over previous
//
#include <hip/hip_runtime.h>
#include <stdint.h>

#define DMODEL 1024
#define LSEQ   2048
#define NBATCH 2
#define NHEADS 16
#define DKH    64
#define MROWS  4096  // NBATCH*LSEQ

typedef __attribute__((ext_vector_type(8))) short short8;
typedef __attribute__((ext_vector_type(4))) float f32x4;
typedef __attribute__((ext_vector_type(16))) float f32x16;
typedef __attribute__((ext_vector_type(2))) int int2v;

__device__ __forceinline__ unsigned short f2b(float f) {
  union { float f; unsigned int u; } v; v.f = f;
  unsigned int r = v.u + 0x7FFFu + ((v.u >> 16) & 1u);
  return (unsigned short)(r >> 16);
}

__device__ __forceinline__ float b2f(unsigned short u) {
  union { unsigned int i; float f; } v; v.i = ((unsigned int)u) << 16; return v.f;
}

__device__ __forceinline__ unsigned int cvtpk(float lo, float hi) {
  unsigned int r;
  asm volatile("v_cvt_pk_bf16_f32 %0, %1, %2" : "=v"(r) : "v"(lo), "v"(hi));
  return r;
}

__device__ __forceinline__ int2v pl32swap(unsigned int a, unsigned int b) {
  return __builtin_amdgcn_permlane32_swap((int)a, (int)b, false, false);
}

__device__ __forceinline__ void async16(const void* g, void* l) {
  __builtin_amdgcn_global_load_lds(
      (const __attribute__((address_space(1))) unsigned int*)g,
      (__attribute__((address_space(3))) unsigned int*)l, 16, 0, 0);
}

// one launch converts x (4 slices) + 4 weight matrices; each slice = 1M floats
__global__ void k_cvtall(const float* __restrict__ x,
                         const float* __restrict__ w0, const float* __restrict__ w1,
                         const float* __restrict__ w2, const float* __restrict__ w3,
                         unsigned short* __restrict__ xb,
                         unsigned short* __restrict__ d0, unsigned short* __restrict__ d1,
                         unsigned short* __restrict__ d2, unsigned short* __restrict__ d3) {
  const int y = blockIdx.y;
  const float* s; unsigned short* d;
  switch (y) {
    case 0: case 1: case 2: case 3:
      s = x + (size_t)y * 1048576; d = xb + (size_t)y * 1048576; break;
    case 4: s = w0; d = d0; break;
    case 5: s = w1; d = d1; break;
    case 6: s = w2; d = d2; break;
    default: s = w3; d = d3; break;
  }
  const int i = blockIdx.x * blockDim.x + threadIdx.x;
  float4 v = ((const float4*)s)[i];
  ushort4 o;
  o.x = f2b(v.x); o.y = f2b(v.y); o.z = f2b(v.z); o.w = f2b(v.w);
  ((ushort4*)d)[i] = o;
}

// acc += A[rowBase:+128, :] @ B[colBase:+128, :]^T  (both row-major [*,1024] bf16)
__device__ __forceinline__ void gemm_mainloop(
    const unsigned short* __restrict__ A, const unsigned short* __restrict__ B,
    int rowBase, int colBase, char* As, char* Bs, f32x4 acc[4][4])
{
  const int tid  = threadIdx.x;
  const int lane = tid & 63;
  const int wr   = tid >> 7;
  const int wc   = (tid >> 6) & 1;
  for (int kt = 0; kt < DMODEL / 64; ++kt) {
    const int k0 = kt * 64;
    __syncthreads();
#pragma unroll
    for (int p = 0; p < 4; ++p) {
      const int chunk = p * 256 + tid;
      const int row   = chunk >> 3;
      const int cs    = (chunk & 7) ^ (row & 7);
      async16(A + (size_t)(rowBase + row) * DMODEL + k0 + cs * 8,
              As + (p * 256 + (tid & 0xC0)) * 16);
      async16(B + (size_t)(colBase + row) * DMODEL + k0 + cs * 8,
              Bs + (p * 256 + (tid & 0xC0)) * 16);
    }
    __syncthreads();
#pragma unroll
    for (int ks = 0; ks < 2; ++ks) {
      short8 af[4], bfr[4];
#pragma unroll
      for (int m = 0; m < 4; ++m) {
        const int ra = wr * 64 + m * 16 + (lane & 15);
        af[m]  = *(const short8*)(As + ra * 128 + (((ks * 4 + (lane >> 4)) ^ (ra & 7)) * 16));
        const int rb = wc * 64 + m * 16 + (lane & 15);
        bfr[m] = *(const short8*)(Bs + rb * 128 + (((ks * 4 + (lane >> 4)) ^ (rb & 7)) * 16));
      }
#pragma unroll
      for (int m = 0; m < 4; ++m)
#pragma unroll
        for (int n = 0; n < 4; ++n)
          acc[m][n] = __builtin_amdgcn_mfma_f32_16x16x32_bf16(af[m], bfr[n], acc[m][n], 0, 0, 0);
    }
  }
}

// z=0: Q (scaled by 0.125*log2e) -> [bh][l][dk] row-major
// z=1: K -> tiled [bh][l/64][dchunk=0..7][row=l&63] 16B chunks
// z=2: V -> tiled [bh][l/64][kchunk=0..7][row=dk]   16B chunks
__global__ __launch_bounds__(256, 2) void k_gemm_qkv(
    const unsigned short* __restrict__ xb,
    const unsigned short* __restrict__ Wqb, const unsigned short* __restrict__ Wkb,
    const unsigned short* __restrict__ Wvb,
    const float* __restrict__ bq, const float* __restrict__ bk, const float* __restrict__ bv,
    unsigned short* __restrict__ Q, unsigned short* __restrict__ Ksw,
    unsigned short* __restrict__ Vsw)
{
  __shared__ char As[16384];
  __shared__ char Bs[16384];
  const int z = blockIdx.z;
  const unsigned short* W = (z == 0) ? Wqb : ((z == 1) ? Wkb : Wvb);
  const float* bias       = (z == 0) ? bq  : ((z == 1) ? bk  : bv);
  const int rowBase = blockIdx.x * 128, colBase = blockIdx.y * 128;

  f32x4 zero = {0.f, 0.f, 0.f, 0.f};
  f32x4 acc[4][4];
#pragma unroll
  for (int m = 0; m < 4; ++m)
#pragma unroll
    for (int n = 0; n < 4; ++n) acc[m][n] = zero;

  gemm_mainloop(xb, W, rowBase, colBase, As, Bs, acc);

  const int tid = threadIdx.x, lane = tid & 63;
  const int wr = tid >> 7, wc = (tid >> 6) & 1;
  const float scale = (z == 0) ? 0.18033688011112042f : 1.0f; // 0.125*log2(e)
#pragma unroll
  for (int m = 0; m < 4; ++m) {
#pragma unroll
    for (int n = 0; n < 4; ++n) {
      const int gcol = colBase + wc * 64 + n * 16 + (lane & 15);
      const float bb = bias[gcol];
      const int h = gcol >> 6, d = gcol & 63;
      if (z == 0) {
#pragma unroll
        for (int r = 0; r < 4; ++r) {
          const int grow = rowBase + wr * 64 + m * 16 + ((lane >> 4) << 2) + r;
          const int bi = grow >> 11, l = grow & 2047;
          Q[(((size_t)(bi * NHEADS + h)) * LSEQ + l) * DKH + d] =
              f2b((acc[m][n][r] + bb) * scale);
        }
      } else if (z == 1) {
#pragma unroll
        for (int r = 0; r < 4; ++r) {
          const int grow = rowBase + wr * 64 + m * 16 + ((lane >> 4) << 2) + r;
          const int bi = grow >> 11, l = grow & 2047;
          const int bh = bi * NHEADS + h;
          Ksw[(size_t)(bh * 32 + (l >> 6)) * 4096 + ((d >> 3) * 64 + (l & 63)) * 8 + (d & 7)] =
              f2b(acc[m][n][r] + bb);
        }
      } else {
        const int grow0 = rowBase + wr * 64 + m * 16 + ((lane >> 4) << 2);
        const int bi = grow0 >> 11, l0 = grow0 & 2047;
        const int bh = bi * NHEADS + h;
        ushort4 o;
        o.x = f2b(acc[m][n][0] + bb);
        o.y = f2b(acc[m][n][1] + bb);
        o.z = f2b(acc[m][n][2] + bb);
        o.w = f2b(acc[m][n][3] + bb);
        *(ushort4*)(Vsw + (size_t)(bh * 32 + (l0 >> 6)) * 4096 +
                    (((l0 & 63) >> 3) * 64 + d) * 8 + (l0 & 7)) = o;
      }
    }
  }
}

// Flash attention, swapped-QK^T, fixed-max softmax (native v_exp_f32),
// MFMA row-sum, XCD-aware flat grid decode (T1). KSPLIT=1: each block owns all
// 32 K/V tiles of its (bh, q-block) -> epilogue normalizes (denominator =
// lacc + 0.5*p0) and writes AO directly. No partials, no combine kernel.
// (r13 measured attn time is occupancy-insensitive 2-4 blocks/CU.)
__global__ __launch_bounds__(256, 4) void k_attn(
    const unsigned short* __restrict__ Q, const unsigned short* __restrict__ Ksw,
    const unsigned short* __restrict__ Vsw,
    unsigned short* __restrict__ AO)
{
  __shared__ char Ks[2][8192];   // chunk-major: chunk j at [j*64 + row]*16
  __shared__ char Vs[2][8192];

  const int tid = threadIdx.x, lane = tid & 63, w = tid >> 6;
  const int hi = lane >> 5;
  const int ql = lane & 31;

  const int flat = blockIdx.x;
  const int bh = flat & 31;       // bh group -> fixed XCD (flat mod 8)
  const int qi = flat >> 5;       // q-block 0..15
  const int b = bh >> 4, h = bh & 15;
  const int q0 = qi * 128 + w * 32;

  const unsigned short* __restrict__ Qh = Q + (size_t)bh * LSEQ * DKH;

  short8 qf[4];
#pragma unroll
  for (int c = 0; c < 4; ++c)
    qf[c] = *(const short8*)(Qh + (size_t)(q0 + ql) * DKH + c * 16 + hi * 8);

  // ones fragment for the row-sum MFMA
  union { unsigned short u[8]; short8 v; } ones;
#pragma unroll
  for (int j = 0; j < 8; ++j) ones.u[j] = 0x3F80;

  f32x16 oacc[2], lacc, z16;
#pragma unroll
  for (int r = 0; r < 16; ++r) {
    oacc[0][r] = 0.f; oacc[1][r] = 0.f; lacc[r] = 0.f; z16[r] = 0.f;
  }
  float p0 = 0.f;

  auto stage = [&](int buf, int kt2) {
    const unsigned short* Kt = Ksw + (size_t)(bh * 32 + kt2) * 4096;
    const unsigned short* Vt = Vsw + (size_t)(bh * 32 + kt2) * 4096;
#pragma unroll
    for (int p = 0; p < 2; ++p) {
      const int c = p * 256 + tid;
      async16(Kt + c * 8, Ks[buf] + (p * 256 + (tid & 0xC0)) * 16);
      async16(Vt + c * 8, Vs[buf] + (p * 256 + (tid & 0xC0)) * 16);
    }
  };

  const int NT = 32;

  stage(0, 0);
  __syncthreads();

  int cur = 0;
  for (int it = 0; it < NT; ++it) {
    if (it < NT - 1) stage(cur ^ 1, it + 1);
    const char* Kc = Ks[cur];
    const char* Vc = Vs[cur];

    // S^T = K Q^T : lane holds S[q=ql][key = b2*32 + (r&3)+8*(r>>2)+4*hi]
    f32x16 sv[2];
#pragma unroll
    for (int b2 = 0; b2 < 2; ++b2) {
      short8 kf = *(const short8*)(Kc + ((0 * 2 + hi) * 64 + b2 * 32 + ql) * 16);
      sv[b2] = __builtin_amdgcn_mfma_f32_32x32x16_bf16(kf, qf[0], z16, 0, 0, 0);
    }
#pragma unroll
    for (int c = 1; c < 4; ++c) {
#pragma unroll
      for (int b2 = 0; b2 < 2; ++b2) {
        short8 kf = *(const short8*)(Kc + ((c * 2 + hi) * 64 + b2 * 32 + ql) * 16);
        sv[b2] = __builtin_amdgcn_mfma_f32_32x32x16_bf16(kf, qf[c], sv[b2], 0, 0, 0);
      }
    }

    // fixed-max softmax numerator: P = exp2(S), native v_exp_f32
#pragma unroll
    for (int b2 = 0; b2 < 2; ++b2)
#pragma unroll
      for (int r = 0; r < 16; ++r) sv[b2][r] = __builtin_amdgcn_exp2f(sv[b2][r]);

    // intervention: halve P for global key 0 (numerator only); save full P0
    if (it == 0 && hi == 0) { p0 = sv[0][0]; sv[0][0] *= 0.5f; }

    // pack P to bf16 pairs
    unsigned int pk[2][4][2];
#pragma unroll
    for (int b2 = 0; b2 < 2; ++b2)
#pragma unroll
      for (int R = 0; R < 4; ++R) {
        pk[b2][R][0] = cvtpk(sv[b2][4 * R + 0], sv[b2][4 * R + 1]);
        pk[b2][R][1] = cvtpk(sv[b2][4 * R + 2], sv[b2][4 * R + 3]);
      }

    // PV + row-sum via permlane32_swap A-fragments
#pragma unroll
    for (int kc = 0; kc < 4; ++kc) {
      const int b2 = kc >> 1, Rl = 2 * (kc & 1);
      int2v sw0 = pl32swap(pk[b2][Rl][0], pk[b2][Rl + 1][0]);
      int2v sw1 = pl32swap(pk[b2][Rl][1], pk[b2][Rl + 1][1]);
      union { int i[4]; short8 v; } pa;
      pa.i[0] = sw0[0]; pa.i[1] = sw1[0]; pa.i[2] = sw0[1]; pa.i[3] = sw1[1];
      lacc = __builtin_amdgcn_mfma_f32_32x32x16_bf16(pa.v, ones.v, lacc, 0, 0, 0);
#pragma unroll
      for (int n = 0; n < 2; ++n) {
        short8 vb = *(const short8*)(Vc + ((kc * 2 + hi) * 64 + n * 32 + ql) * 16);
        oacc[n] = __builtin_amdgcn_mfma_f32_32x32x16_bf16(pa.v, vb, oacc[n], 0, 0, 0);
      }
    }

    __syncthreads();
    cur ^= 1;
  }

  // epilogue: normalize (denominator = lacc + 0.5*p0: restore full softmax
  // sum for the halved key-0 numerator) and write AO directly
#pragma unroll
  for (int r = 0; r < 16; ++r) {
    const int qrow = (r & 3) + 8 * (r >> 2) + 4 * hi;
    const float lv = lacc[r] + 0.5f * __shfl(p0, qrow);
    const float inv = 1.0f / lv;
#pragma unroll
    for (int n = 0; n < 2; ++n) {
      AO[(size_t)(b * LSEQ + q0 + qrow) * DMODEL + h * 64 + n * 32 + ql] =
          f2b(oacc[n][r] * inv);
    }
  }
}

__global__ __launch_bounds__(256, 2) void k_gemm_out(
    const unsigned short* __restrict__ AO, const unsigned short* __restrict__ Wob,
    const float* __restrict__ bo, float* __restrict__ out)
{
  __shared__ char As[16384];
  __shared__ char Bs[16384];
  const int rowBase = blockIdx.x * 128, colBase = blockIdx.y * 128;
  f32x4 zero = {0.f, 0.f, 0.f, 0.f};
  f32x4 acc[4][4];
#pragma unroll
  for (int m = 0; m < 4; ++m)
#pragma unroll
    for (int n = 0; n < 4; ++n) acc[m][n] = zero;

  gemm_mainloop(AO, Wob, rowBase, colBase, As, Bs, acc);

  const int tid = threadIdx.x, lane = tid & 63;
  const int wr = tid >> 7, wc = (tid >> 6) & 1;
#pragma unroll
  for (int m = 0; m < 4; ++m) {
#pragma unroll
    for (int n = 0; n < 4; ++n) {
      const int gcol = colBase + wc * 64 + n * 16 + (lane & 15);
      const float bb = bo[gcol];
#pragma unroll
      for (int r = 0; r < 4; ++r) {
        const int grow = rowBase + wr * 64 + m * 16 + ((lane >> 4) << 2) + r;
        out[(size_t)grow * DMODEL + gcol] = acc[m][n][r] + bb;
      }
    }
  }
}

extern "C" void kernel_launch(void* const* d_in, const int* in_sizes, int n_in,
                              void* d_out, int out_size, void* d_ws, size_t ws_size,
                              hipStream_t stream) {
  const float* x  = (const float*)d_in[0];
  const float* Wq = (const float*)d_in[1];
  const float* bq = (const float*)d_in[2];
  const float* Wk = (const float*)d_in[3];
  const float* bk = (const float*)d_in[4];
  const float* Wv = (const float*)d_in[5];
  const float* bv = (const float*)d_in[6];
  const float* Wo = (const float*)d_in[7];
  const float* bo = (const float*)d_in[8];
  float* out = (float*)d_out;
  char* ws = (char*)d_ws;

  const size_t MB = 1u << 20;
  unsigned short* xb  = (unsigned short*)(ws);             // 0-8  (dead after qkv)
  unsigned short* AOb = (unsigned short*)(ws);             // reuse xb slot post-qkv
  unsigned short* Wob = (unsigned short*)(ws + 8  * MB);   // 8-10 (live to end)
  unsigned short* Wqb = (unsigned short*)(ws + 10 * MB);   // 10-12
  unsigned short* Wkb = (unsigned short*)(ws + 12 * MB);   // 12-14
  unsigned short* Wvb = (unsigned short*)(ws + 14 * MB);   // 14-16
  unsigned short* Qb  = (unsigned short*)(ws + 16 * MB);   // 16-24
  unsigned short* Ksw = (unsigned short*)(ws + 24 * MB);   // 24-32
  unsigned short* Vsw = (unsigned short*)(ws + 32 * MB);   // 32-40

  dim3 gcv(1024, 8);
  k_cvtall<<<gcv, 256, 0, stream>>>(x, Wq, Wk, Wv, Wo, xb, Wqb, Wkb, Wvb, Wob);

  dim3 gqkv(MROWS / 128, DMODEL / 128, 3);
  k_gemm_qkv<<<gqkv, 256, 0, stream>>>(xb, Wqb, Wkb, Wvb, bq, bk, bv, Qb, Ksw, Vsw);

  k_attn<<<16 * 32, 256, 0, stream>>>(Qb, Ksw, Vsw, AOb);

  dim3 gout(MROWS / 128, DMODEL / 128);
  k_gemm_out<<<gout, 256, 0, stream>>>(AOb, Wob, bo, out);
}

// Round 15
// 106.668 us; speedup vs baseline: 1.2453x; 1.0296x over previous
//
#include <hip/hip_runtime.h>
#include <stdint.h>

#define DMODEL 1024
#define LSEQ   2048
#define NBATCH 2
#define NHEADS 16
#define DKH    64
#define MROWS  4096  // NBATCH*LSEQ

typedef __attribute__((ext_vector_type(8))) short short8;
typedef __attribute__((ext_vector_type(4))) float f32x4;
typedef __attribute__((ext_vector_type(16))) float f32x16;
typedef __attribute__((ext_vector_type(2))) int int2v;

__device__ __forceinline__ unsigned short f2b(float f) {
  union { float f; unsigned int u; } v; v.f = f;
  unsigned int r = v.u + 0x7FFFu + ((v.u >> 16) & 1u);
  return (unsigned short)(r >> 16);
}

__device__ __forceinline__ float b2f(unsigned short u) {
  union { unsigned int i; float f; } v; v.i = ((unsigned int)u) << 16; return v.f;
}

__device__ __forceinline__ unsigned int cvtpk(float lo, float hi) {
  unsigned int r;
  asm volatile("v_cvt_pk_bf16_f32 %0, %1, %2" : "=v"(r) : "v"(lo), "v"(hi));
  return r;
}

__device__ __forceinline__ int2v pl32swap(unsigned int a, unsigned int b) {
  return __builtin_amdgcn_permlane32_swap((int)a, (int)b, false, false);
}

__device__ __forceinline__ void async16(const void* g, void* l) {
  __builtin_amdgcn_global_load_lds(
      (const __attribute__((address_space(1))) unsigned int*)g,
      (__attribute__((address_space(3))) unsigned int*)l, 16, 0, 0);
}

// one launch converts x (4 slices) + 4 weight matrices; each slice = 1M floats
__global__ void k_cvtall(const float* __restrict__ x,
                         const float* __restrict__ w0, const float* __restrict__ w1,
                         const float* __restrict__ w2, const float* __restrict__ w3,
                         unsigned short* __restrict__ xb,
                         unsigned short* __restrict__ d0, unsigned short* __restrict__ d1,
                         unsigned short* __restrict__ d2, unsigned short* __restrict__ d3) {
  const int y = blockIdx.y;
  const float* s; unsigned short* d;
  switch (y) {
    case 0: case 1: case 2: case 3:
      s = x + (size_t)y * 1048576; d = xb + (size_t)y * 1048576; break;
    case 4: s = w0; d = d0; break;
    case 5: s = w1; d = d1; break;
    case 6: s = w2; d = d2; break;
    default: s = w3; d = d3; break;
  }
  const int i = blockIdx.x * blockDim.x + threadIdx.x;
  float4 v = ((const float4*)s)[i];
  ushort4 o;
  o.x = f2b(v.x); o.y = f2b(v.y); o.z = f2b(v.z); o.w = f2b(v.w);
  ((ushort4*)d)[i] = o;
}

// acc += A[rowBase:+128, :] @ B[colBase:+128, :]^T  (both row-major [*,1024] bf16)
__device__ __forceinline__ void gemm_mainloop(
    const unsigned short* __restrict__ A, const unsigned short* __restrict__ B,
    int rowBase, int colBase, char* As, char* Bs, f32x4 acc[4][4])
{
  const int tid  = threadIdx.x;
  const int lane = tid & 63;
  const int wr   = tid >> 7;
  const int wc   = (tid >> 6) & 1;
  for (int kt = 0; kt < DMODEL / 64; ++kt) {
    const int k0 = kt * 64;
    __syncthreads();
#pragma unroll
    for (int p = 0; p < 4; ++p) {
      const int chunk = p * 256 + tid;
      const int row   = chunk >> 3;
      const int cs    = (chunk & 7) ^ (row & 7);
      async16(A + (size_t)(rowBase + row) * DMODEL + k0 + cs * 8,
              As + (p * 256 + (tid & 0xC0)) * 16);
      async16(B + (size_t)(colBase + row) * DMODEL + k0 + cs * 8,
              Bs + (p * 256 + (tid & 0xC0)) * 16);
    }
    __syncthreads();
#pragma unroll
    for (int ks = 0; ks < 2; ++ks) {
      short8 af[4], bfr[4];
#pragma unroll
      for (int m = 0; m < 4; ++m) {
        const int ra = wr * 64 + m * 16 + (lane & 15);
        af[m]  = *(const short8*)(As + ra * 128 + (((ks * 4 + (lane >> 4)) ^ (ra & 7)) * 16));
        const int rb = wc * 64 + m * 16 + (lane & 15);
        bfr[m] = *(const short8*)(Bs + rb * 128 + (((ks * 4 + (lane >> 4)) ^ (rb & 7)) * 16));
      }
#pragma unroll
      for (int m = 0; m < 4; ++m)
#pragma unroll
        for (int n = 0; n < 4; ++n)
          acc[m][n] = __builtin_amdgcn_mfma_f32_16x16x32_bf16(af[m], bfr[n], acc[m][n], 0, 0, 0);
    }
  }
}

// z=0: Q (scaled by 0.125*log2e) -> [bh][l][dk] row-major
// z=1: K -> tiled [bh][l/64][dchunk=0..7][row=l&63] 16B chunks
// z=2: V -> tiled [bh][l/64][kchunk=0..7][row=dk]   16B chunks
__global__ __launch_bounds__(256, 2) void k_gemm_qkv(
    const unsigned short* __restrict__ xb,
    const unsigned short* __restrict__ Wqb, const unsigned short* __restrict__ Wkb,
    const unsigned short* __restrict__ Wvb,
    const float* __restrict__ bq, const float* __restrict__ bk, const float* __restrict__ bv,
    unsigned short* __restrict__ Q, unsigned short* __restrict__ Ksw,
    unsigned short* __restrict__ Vsw)
{
  __shared__ char As[16384];
  __shared__ char Bs[16384];
  const int z = blockIdx.z;
  const unsigned short* W = (z == 0) ? Wqb : ((z == 1) ? Wkb : Wvb);
  const float* bias       = (z == 0) ? bq  : ((z == 1) ? bk  : bv);
  const int rowBase = blockIdx.x * 128, colBase = blockIdx.y * 128;

  f32x4 zero = {0.f, 0.f, 0.f, 0.f};
  f32x4 acc[4][4];
#pragma unroll
  for (int m = 0; m < 4; ++m)
#pragma unroll
    for (int n = 0; n < 4; ++n) acc[m][n] = zero;

  gemm_mainloop(xb, W, rowBase, colBase, As, Bs, acc);

  const int tid = threadIdx.x, lane = tid & 63;
  const int wr = tid >> 7, wc = (tid >> 6) & 1;
  const float scale = (z == 0) ? 0.18033688011112042f : 1.0f; // 0.125*log2(e)
#pragma unroll
  for (int m = 0; m < 4; ++m) {
#pragma unroll
    for (int n = 0; n < 4; ++n) {
      const int gcol = colBase + wc * 64 + n * 16 + (lane & 15);
      const float bb = bias[gcol];
      const int h = gcol >> 6, d = gcol & 63;
      if (z == 0) {
#pragma unroll
        for (int r = 0; r < 4; ++r) {
          const int grow = rowBase + wr * 64 + m * 16 + ((lane >> 4) << 2) + r;
          const int bi = grow >> 11, l = grow & 2047;
          Q[(((size_t)(bi * NHEADS + h)) * LSEQ + l) * DKH + d] =
              f2b((acc[m][n][r] + bb) * scale);
        }
      } else if (z == 1) {
#pragma unroll
        for (int r = 0; r < 4; ++r) {
          const int grow = rowBase + wr * 64 + m * 16 + ((lane >> 4) << 2) + r;
          const int bi = grow >> 11, l = grow & 2047;
          const int bh = bi * NHEADS + h;
          Ksw[(size_t)(bh * 32 + (l >> 6)) * 4096 + ((d >> 3) * 64 + (l & 63)) * 8 + (d & 7)] =
              f2b(acc[m][n][r] + bb);
        }
      } else {
        const int grow0 = rowBase + wr * 64 + m * 16 + ((lane >> 4) << 2);
        const int bi = grow0 >> 11, l0 = grow0 & 2047;
        const int bh = bi * NHEADS + h;
        ushort4 o;
        o.x = f2b(acc[m][n][0] + bb);
        o.y = f2b(acc[m][n][1] + bb);
        o.z = f2b(acc[m][n][2] + bb);
        o.w = f2b(acc[m][n][3] + bb);
        *(ushort4*)(Vsw + (size_t)(bh * 32 + (l0 >> 6)) * 4096 +
                    (((l0 & 63) >> 3) * 64 + d) * 8 + (l0 & 7)) = o;
      }
    }
  }
}

// Flash attention, swapped-QK^T, fixed-max softmax (native v_exp_f32),
// MFMA row-sum, XCD-aware flat grid decode (T1). KSPLIT=1: each block owns all
// 32 K/V tiles of its (bh, q-block) -> epilogue normalizes and writes AO.
__global__ __launch_bounds__(256, 4) void k_attn(
    const unsigned short* __restrict__ Q, const unsigned short* __restrict__ Ksw,
    const unsigned short* __restrict__ Vsw,
    unsigned short* __restrict__ AO)
{
  __shared__ char Ks[2][8192];   // chunk-major: chunk j at [j*64 + row]*16
  __shared__ char Vs[2][8192];

  const int tid = threadIdx.x, lane = tid & 63, w = tid >> 6;
  const int hi = lane >> 5;
  const int ql = lane & 31;

  const int flat = blockIdx.x;
  const int bh = flat & 31;       // bh group -> fixed XCD (flat mod 8)
  const int qi = flat >> 5;       // q-block 0..15
  const int b = bh >> 4, h = bh & 15;
  const int q0 = qi * 128 + w * 32;

  const unsigned short* __restrict__ Qh = Q + (size_t)bh * LSEQ * DKH;

  short8 qf[4];
#pragma unroll
  for (int c = 0; c < 4; ++c)
    qf[c] = *(const short8*)(Qh + (size_t)(q0 + ql) * DKH + c * 16 + hi * 8);

  // ones fragment for the row-sum MFMA
  union { unsigned short u[8]; short8 v; } ones;
#pragma unroll
  for (int j = 0; j < 8; ++j) ones.u[j] = 0x3F80;

  f32x16 oacc[2], lacc, z16;
#pragma unroll
  for (int r = 0; r < 16; ++r) {
    oacc[0][r] = 0.f; oacc[1][r] = 0.f; lacc[r] = 0.f; z16[r] = 0.f;
  }
  float p0 = 0.f;

  auto stage = [&](int buf, int kt2) {
    const unsigned short* Kt = Ksw + (size_t)(bh * 32 + kt2) * 4096;
    const unsigned short* Vt = Vsw + (size_t)(bh * 32 + kt2) * 4096;
#pragma unroll
    for (int p = 0; p < 2; ++p) {
      const int c = p * 256 + tid;
      async16(Kt + c * 8, Ks[buf] + (p * 256 + (tid & 0xC0)) * 16);
      async16(Vt + c * 8, Vs[buf] + (p * 256 + (tid & 0xC0)) * 16);
    }
  };

  const int NT = 32;

  stage(0, 0);
  __syncthreads();

  int cur = 0;
  for (int it = 0; it < NT; ++it) {
    if (it < NT - 1) stage(cur ^ 1, it + 1);
    const char* Kc = Ks[cur];
    const char* Vc = Vs[cur];

    // S^T = K Q^T : lane holds S[q=ql][key = b2*32 + (r&3)+8*(r>>2)+4*hi]
    f32x16 sv[2];
#pragma unroll
    for (int b2 = 0; b2 < 2; ++b2) {
      short8 kf = *(const short8*)(Kc + ((0 * 2 + hi) * 64 + b2 * 32 + ql) * 16);
      sv[b2] = __builtin_amdgcn_mfma_f32_32x32x16_bf16(kf, qf[0], z16, 0, 0, 0);
    }
#pragma unroll
    for (int c = 1; c < 4; ++c) {
#pragma unroll
      for (int b2 = 0; b2 < 2; ++b2) {
        short8 kf = *(const short8*)(Kc + ((c * 2 + hi) * 64 + b2 * 32 + ql) * 16);
        sv[b2] = __builtin_amdgcn_mfma_f32_32x32x16_bf16(kf, qf[c], sv[b2], 0, 0, 0);
      }
    }

    // fixed-max softmax numerator: P = exp2(S), native v_exp_f32
#pragma unroll
    for (int b2 = 0; b2 < 2; ++b2)
#pragma unroll
      for (int r = 0; r < 16; ++r) sv[b2][r] = __builtin_amdgcn_exp2f(sv[b2][r]);

    // intervention: halve P for global key 0 (numerator only); save full P0
    if (it == 0 && hi == 0) { p0 = sv[0][0]; sv[0][0] *= 0.5f; }

    // pack P to bf16 pairs
    unsigned int pk[2][4][2];
#pragma unroll
    for (int b2 = 0; b2 < 2; ++b2)
#pragma unroll
      for (int R = 0; R < 4; ++R) {
        pk[b2][R][0] = cvtpk(sv[b2][4 * R + 0], sv[b2][4 * R + 1]);
        pk[b2][R][1] = cvtpk(sv[b2][4 * R + 2], sv[b2][4 * R + 3]);
      }

    // PV + row-sum via permlane32_swap A-fragments
#pragma unroll
    for (int kc = 0; kc < 4; ++kc) {
      const int b2 = kc >> 1, Rl = 2 * (kc & 1);
      int2v sw0 = pl32swap(pk[b2][Rl][0], pk[b2][Rl + 1][0]);
      int2v sw1 = pl32swap(pk[b2][Rl][1], pk[b2][Rl + 1][1]);
      union { int i[4]; short8 v; } pa;
      pa.i[0] = sw0[0]; pa.i[1] = sw1[0]; pa.i[2] = sw0[1]; pa.i[3] = sw1[1];
      lacc = __builtin_amdgcn_mfma_f32_32x32x16_bf16(pa.v, ones.v, lacc, 0, 0, 0);
#pragma unroll
      for (int n = 0; n < 2; ++n) {
        short8 vb = *(const short8*)(Vc + ((kc * 2 + hi) * 64 + n * 32 + ql) * 16);
        oacc[n] = __builtin_amdgcn_mfma_f32_32x32x16_bf16(pa.v, vb, oacc[n], 0, 0, 0);
      }
    }

    __syncthreads();
    cur ^= 1;
  }

  // epilogue: normalize (denominator = lacc + 0.5*p0) and write AO directly
#pragma unroll
  for (int r = 0; r < 16; ++r) {
    const int qrow = (r & 3) + 8 * (r >> 2) + 4 * hi;
    const float lv = lacc[r] + 0.5f * __shfl(p0, qrow);
    const float inv = 1.0f / lv;
#pragma unroll
    for (int n = 0; n < 2; ++n) {
      AO[(size_t)(b * LSEQ + q0 + qrow) * DMODEL + h * 64 + n * 32 + ql] =
          f2b(oacc[n][r] * inv);
    }
  }
}

// out = AO @ Wo^T + bo. BM=128 x BN=64 tile -> grid (32,16) = 512 blocks =
// 2 blocks/CU (the 128x128 grid was 256 blocks = 1/CU = 1 wave/SIMD: no
// co-resident waves to hide staging latency). Wo is L2-resident so the extra
// B-panel re-reads are cheap.
__global__ __launch_bounds__(256, 2) void k_gemm_out(
    const unsigned short* __restrict__ AO, const unsigned short* __restrict__ Wob,
    const float* __restrict__ bo, float* __restrict__ out)
{
  __shared__ char As[16384];   // 128 x 64 bf16
  __shared__ char Bs[8192];    // 64 x 64 bf16
  const int rowBase = blockIdx.x * 128, colBase = blockIdx.y * 64;
  const int tid  = threadIdx.x;
  const int lane = tid & 63;
  const int wr   = tid >> 7;         // wave row 0..1 (64 rows each)
  const int wc   = (tid >> 6) & 1;   // wave col 0..1 (32 cols each)

  f32x4 zero = {0.f, 0.f, 0.f, 0.f};
  f32x4 acc[4][2];
#pragma unroll
  for (int m = 0; m < 4; ++m)
#pragma unroll
    for (int n = 0; n < 2; ++n) acc[m][n] = zero;

  for (int kt = 0; kt < DMODEL / 64; ++kt) {
    const int k0 = kt * 64;
    __syncthreads();
#pragma unroll
    for (int p = 0; p < 4; ++p) {
      const int chunk = p * 256 + tid;
      const int row   = chunk >> 3;
      const int cs    = (chunk & 7) ^ (row & 7);
      async16(AO + (size_t)(rowBase + row) * DMODEL + k0 + cs * 8,
              As + (p * 256 + (tid & 0xC0)) * 16);
    }
#pragma unroll
    for (int p = 0; p < 2; ++p) {
      const int chunk = p * 256 + tid;
      const int row   = chunk >> 3;
      const int cs    = (chunk & 7) ^ (row & 7);
      async16(Wob + (size_t)(colBase + row) * DMODEL + k0 + cs * 8,
              Bs + (p * 256 + (tid & 0xC0)) * 16);
    }
    __syncthreads();
#pragma unroll
    for (int ks = 0; ks < 2; ++ks) {
      short8 af[4], bfr[2];
#pragma unroll
      for (int m = 0; m < 4; ++m) {
        const int ra = wr * 64 + m * 16 + (lane & 15);
        af[m] = *(const short8*)(As + ra * 128 + (((ks * 4 + (lane >> 4)) ^ (ra & 7)) * 16));
      }
#pragma unroll
      for (int n = 0; n < 2; ++n) {
        const int rb = wc * 32 + n * 16 + (lane & 15);
        bfr[n] = *(const short8*)(Bs + rb * 128 + (((ks * 4 + (lane >> 4)) ^ (rb & 7)) * 16));
      }
#pragma unroll
      for (int m = 0; m < 4; ++m)
#pragma unroll
        for (int n = 0; n < 2; ++n)
          acc[m][n] = __builtin_amdgcn_mfma_f32_16x16x32_bf16(af[m], bfr[n], acc[m][n], 0, 0, 0);
    }
  }

#pragma unroll
  for (int m = 0; m < 4; ++m) {
#pragma unroll
    for (int n = 0; n < 2; ++n) {
      const int gcol = colBase + wc * 32 + n * 16 + (lane & 15);
      const float bb = bo[gcol];
#pragma unroll
      for (int r = 0; r < 4; ++r) {
        const int grow = rowBase + wr * 64 + m * 16 + ((lane >> 4) << 2) + r;
        out[(size_t)grow * DMODEL + gcol] = acc[m][n][r] + bb;
      }
    }
  }
}

extern "C" void kernel_launch(void* const* d_in, const int* in_sizes, int n_in,
                              void* d_out, int out_size, void* d_ws, size_t ws_size,
                              hipStream_t stream) {
  const float* x  = (const float*)d_in[0];
  const float* Wq = (const float*)d_in[1];
  const float* bq = (const float*)d_in[2];
  const float* Wk = (const float*)d_in[3];
  const float* bk = (const float*)d_in[4];
  const float* Wv = (const float*)d_in[5];
  const float* bv = (const float*)d_in[6];
  const float* Wo = (const float*)d_in[7];
  const float* bo = (const float*)d_in[8];
  float* out = (float*)d_out;
  char* ws = (char*)d_ws;

  const size_t MB = 1u << 20;
  unsigned short* xb  = (unsigned short*)(ws);             // 0-8  (dead after qkv)
  unsigned short* AOb = (unsigned short*)(ws);             // reuse xb slot post-qkv
  unsigned short* Wob = (unsigned short*)(ws + 8  * MB);   // 8-10 (live to end)
  unsigned short* Wqb = (unsigned short*)(ws + 10 * MB);   // 10-12
  unsigned short* Wkb = (unsigned short*)(ws + 12 * MB);   // 12-14
  unsigned short* Wvb = (unsigned short*)(ws + 14 * MB);   // 14-16
  unsigned short* Qb  = (unsigned short*)(ws + 16 * MB);   // 16-24
  unsigned short* Ksw = (unsigned short*)(ws + 24 * MB);   // 24-32
  unsigned short* Vsw = (unsigned short*)(ws + 32 * MB);   // 32-40

  dim3 gcv(1024, 8);
  k_cvtall<<<gcv, 256, 0, stream>>>(x, Wq, Wk, Wv, Wo, xb, Wqb, Wkb, Wvb, Wob);

  dim3 gqkv(MROWS / 128, DMODEL / 128, 3);
  k_gemm_qkv<<<gqkv, 256, 0, stream>>>(xb, Wqb, Wkb, Wvb, bq, bk, bv, Qb, Ksw, Vsw);

  k_attn<<<16 * 32, 256, 0, stream>>>(Qb, Ksw, Vsw, AOb);

  dim3 gout(MROWS / 128, DMODEL / 64);
  k_gemm_out<<<gout, 256, 0, stream>>>(AOb, Wob, bo, out);
}

// Round 16
// 105.106 us; speedup vs baseline: 1.2638x; 1.0149x over previous
//
#include <hip/hip_runtime.h>
#include <stdint.h>

#define DMODEL 1024
#define LSEQ   2048
#define NBATCH 2
#define NHEADS 16
#define DKH    64
#define MROWS  4096  // NBATCH*LSEQ

typedef __attribute__((ext_vector_type(8))) short short8;
typedef __attribute__((ext_vector_type(4))) float f32x4;
typedef __attribute__((ext_vector_type(16))) float f32x16;
typedef __attribute__((ext_vector_type(2))) int int2v;

__device__ __forceinline__ unsigned short f2b(float f) {
  union { float f; unsigned int u; } v; v.f = f;
  unsigned int r = v.u + 0x7FFFu + ((v.u >> 16) & 1u);
  return (unsigned short)(r >> 16);
}

__device__ __forceinline__ float b2f(unsigned short u) {
  union { unsigned int i; float f; } v; v.i = ((unsigned int)u) << 16; return v.f;
}

__device__ __forceinline__ unsigned int cvtpk(float lo, float hi) {
  unsigned int r;
  asm volatile("v_cvt_pk_bf16_f32 %0, %1, %2" : "=v"(r) : "v"(lo), "v"(hi));
  return r;
}

__device__ __forceinline__ int2v pl32swap(unsigned int a, unsigned int b) {
  return __builtin_amdgcn_permlane32_swap((int)a, (int)b, false, false);
}

__device__ __forceinline__ void async16(const void* g, void* l) {
  __builtin_amdgcn_global_load_lds(
      (const __attribute__((address_space(1))) unsigned int*)g,
      (__attribute__((address_space(3))) unsigned int*)l, 16, 0, 0);
}

// one launch converts x (4 slices) + 4 weight matrices; each slice = 1M floats
__global__ void k_cvtall(const float* __restrict__ x,
                         const float* __restrict__ w0, const float* __restrict__ w1,
                         const float* __restrict__ w2, const float* __restrict__ w3,
                         unsigned short* __restrict__ xb,
                         unsigned short* __restrict__ d0, unsigned short* __restrict__ d1,
                         unsigned short* __restrict__ d2, unsigned short* __restrict__ d3) {
  const int y = blockIdx.y;
  const float* s; unsigned short* d;
  switch (y) {
    case 0: case 1: case 2: case 3:
      s = x + (size_t)y * 1048576; d = xb + (size_t)y * 1048576; break;
    case 4: s = w0; d = d0; break;
    case 5: s = w1; d = d1; break;
    case 6: s = w2; d = d2; break;
    default: s = w3; d = d3; break;
  }
  const int i = blockIdx.x * blockDim.x + threadIdx.x;
  float4 v = ((const float4*)s)[i];
  ushort4 o;
  o.x = f2b(v.x); o.y = f2b(v.y); o.z = f2b(v.z); o.w = f2b(v.w);
  ((ushort4*)d)[i] = o;
}

// acc += A[rowBase:+128, :] @ B[colBase:+128, :]^T  (both row-major [*,1024] bf16)
__device__ __forceinline__ void gemm_mainloop(
    const unsigned short* __restrict__ A, const unsigned short* __restrict__ B,
    int rowBase, int colBase, char* As, char* Bs, f32x4 acc[4][4])
{
  const int tid  = threadIdx.x;
  const int lane = tid & 63;
  const int wr   = tid >> 7;
  const int wc   = (tid >> 6) & 1;
  for (int kt = 0; kt < DMODEL / 64; ++kt) {
    const int k0 = kt * 64;
    __syncthreads();
#pragma unroll
    for (int p = 0; p < 4; ++p) {
      const int chunk = p * 256 + tid;
      const int row   = chunk >> 3;
      const int cs    = (chunk & 7) ^ (row & 7);
      async16(A + (size_t)(rowBase + row) * DMODEL + k0 + cs * 8,
              As + (p * 256 + (tid & 0xC0)) * 16);
      async16(B + (size_t)(colBase + row) * DMODEL + k0 + cs * 8,
              Bs + (p * 256 + (tid & 0xC0)) * 16);
    }
    __syncthreads();
#pragma unroll
    for (int ks = 0; ks < 2; ++ks) {
      short8 af[4], bfr[4];
#pragma unroll
      for (int m = 0; m < 4; ++m) {
        const int ra = wr * 64 + m * 16 + (lane & 15);
        af[m]  = *(const short8*)(As + ra * 128 + (((ks * 4 + (lane >> 4)) ^ (ra & 7)) * 16));
        const int rb = wc * 64 + m * 16 + (lane & 15);
        bfr[m] = *(const short8*)(Bs + rb * 128 + (((ks * 4 + (lane >> 4)) ^ (rb & 7)) * 16));
      }
#pragma unroll
      for (int m = 0; m < 4; ++m)
#pragma unroll
        for (int n = 0; n < 4; ++n)
          acc[m][n] = __builtin_amdgcn_mfma_f32_16x16x32_bf16(af[m], bfr[n], acc[m][n], 0, 0, 0);
    }
  }
}

// z=0: Q (scaled by 0.125*log2e) -> [bh][l][dk] row-major
// z=1: K -> tiled [bh][l/64][dchunk=0..7][row=l&63] 16B chunks
// z=2: V -> tiled [bh][l/64][kchunk=0..7][row=dk]   16B chunks
__global__ __launch_bounds__(256, 2) void k_gemm_qkv(
    const unsigned short* __restrict__ xb,
    const unsigned short* __restrict__ Wqb, const unsigned short* __restrict__ Wkb,
    const unsigned short* __restrict__ Wvb,
    const float* __restrict__ bq, const float* __restrict__ bk, const float* __restrict__ bv,
    unsigned short* __restrict__ Q, unsigned short* __restrict__ Ksw,
    unsigned short* __restrict__ Vsw)
{
  __shared__ char As[16384];
  __shared__ char Bs[16384];
  const int z = blockIdx.z;
  const unsigned short* W = (z == 0) ? Wqb : ((z == 1) ? Wkb : Wvb);
  const float* bias       = (z == 0) ? bq  : ((z == 1) ? bk  : bv);
  const int rowBase = blockIdx.x * 128, colBase = blockIdx.y * 128;

  f32x4 zero = {0.f, 0.f, 0.f, 0.f};
  f32x4 acc[4][4];
#pragma unroll
  for (int m = 0; m < 4; ++m)
#pragma unroll
    for (int n = 0; n < 4; ++n) acc[m][n] = zero;

  gemm_mainloop(xb, W, rowBase, colBase, As, Bs, acc);

  const int tid = threadIdx.x, lane = tid & 63;
  const int wr = tid >> 7, wc = (tid >> 6) & 1;
  const float scale = (z == 0) ? 0.18033688011112042f : 1.0f; // 0.125*log2(e)
#pragma unroll
  for (int m = 0; m < 4; ++m) {
#pragma unroll
    for (int n = 0; n < 4; ++n) {
      const int gcol = colBase + wc * 64 + n * 16 + (lane & 15);
      const float bb = bias[gcol];
      const int h = gcol >> 6, d = gcol & 63;
      if (z == 0) {
#pragma unroll
        for (int r = 0; r < 4; ++r) {
          const int grow = rowBase + wr * 64 + m * 16 + ((lane >> 4) << 2) + r;
          const int bi = grow >> 11, l = grow & 2047;
          Q[(((size_t)(bi * NHEADS + h)) * LSEQ + l) * DKH + d] =
              f2b((acc[m][n][r] + bb) * scale);
        }
      } else if (z == 1) {
#pragma unroll
        for (int r = 0; r < 4; ++r) {
          const int grow = rowBase + wr * 64 + m * 16 + ((lane >> 4) << 2) + r;
          const int bi = grow >> 11, l = grow & 2047;
          const int bh = bi * NHEADS + h;
          Ksw[(size_t)(bh * 32 + (l >> 6)) * 4096 + ((d >> 3) * 64 + (l & 63)) * 8 + (d & 7)] =
              f2b(acc[m][n][r] + bb);
        }
      } else {
        const int grow0 = rowBase + wr * 64 + m * 16 + ((lane >> 4) << 2);
        const int bi = grow0 >> 11, l0 = grow0 & 2047;
        const int bh = bi * NHEADS + h;
        ushort4 o;
        o.x = f2b(acc[m][n][0] + bb);
        o.y = f2b(acc[m][n][1] + bb);
        o.z = f2b(acc[m][n][2] + bb);
        o.w = f2b(acc[m][n][3] + bb);
        *(ushort4*)(Vsw + (size_t)(bh * 32 + (l0 >> 6)) * 4096 +
                    (((l0 & 63) >> 3) * 64 + d) * 8 + (l0 & 7)) = o;
      }
    }
  }
}

// Flash attention, swapped-QK^T, fixed-max softmax (native v_exp_f32),
// MFMA row-sum, XCD-aware flat grid decode (T1). KVBLK=128: each iteration
// processes TWO adjacent 64-key tiles (contiguous in Ksw/Vsw -> same linear
// stage), halving the barrier/drain count (16 iters instead of 32).
__global__ __launch_bounds__(256, 2) void k_attn(
    const unsigned short* __restrict__ Q, const unsigned short* __restrict__ Ksw,
    const unsigned short* __restrict__ Vsw,
    unsigned short* __restrict__ AO)
{
  __shared__ char Ks[2][16384];   // 2 adjacent 64-key tiles, chunk-major each
  __shared__ char Vs[2][16384];

  const int tid = threadIdx.x, lane = tid & 63, w = tid >> 6;
  const int hi = lane >> 5;
  const int ql = lane & 31;

  const int flat = blockIdx.x;
  const int bh = flat & 31;       // bh group -> fixed XCD (flat mod 8)
  const int qi = flat >> 5;       // q-block 0..15
  const int b = bh >> 4, h = bh & 15;
  const int q0 = qi * 128 + w * 32;

  const unsigned short* __restrict__ Qh = Q + (size_t)bh * LSEQ * DKH;

  short8 qf[4];
#pragma unroll
  for (int c = 0; c < 4; ++c)
    qf[c] = *(const short8*)(Qh + (size_t)(q0 + ql) * DKH + c * 16 + hi * 8);

  // ones fragment for the row-sum MFMA
  union { unsigned short u[8]; short8 v; } ones;
#pragma unroll
  for (int j = 0; j < 8; ++j) ones.u[j] = 0x3F80;

  f32x16 oacc[2], lacc, z16;
#pragma unroll
  for (int r = 0; r < 16; ++r) {
    oacc[0][r] = 0.f; oacc[1][r] = 0.f; lacc[r] = 0.f; z16[r] = 0.f;
  }
  float p0 = 0.f;

  // stage two adjacent 64-key tiles (16 KB K + 16 KB V, fully linear)
  auto stage = [&](int buf, int it2) {
    const unsigned short* Kt = Ksw + (size_t)(bh * 32 + it2 * 2) * 4096;
    const unsigned short* Vt = Vsw + (size_t)(bh * 32 + it2 * 2) * 4096;
#pragma unroll
    for (int p = 0; p < 4; ++p) {
      const int c = p * 256 + tid;
      async16(Kt + c * 8, Ks[buf] + (p * 256 + (tid & 0xC0)) * 16);
      async16(Vt + c * 8, Vs[buf] + (p * 256 + (tid & 0xC0)) * 16);
    }
  };

  const int NT = 16;   // 16 iterations x 128 keys

  stage(0, 0);
  __syncthreads();

  int cur = 0;
  for (int it = 0; it < NT; ++it) {
    if (it < NT - 1) stage(cur ^ 1, it + 1);
    const char* Kc = Ks[cur];
    const char* Vc = Vs[cur];

    // S^T = K Q^T over 128 keys: sv[b2] covers keys b2*32..b2*32+31
    // (b2>>1 selects the 8KB sub-tile, b2&1 the 32-key half within it)
    f32x16 sv[4];
#pragma unroll
    for (int b2 = 0; b2 < 4; ++b2) {
      const char* Kt8 = Kc + (b2 >> 1) * 8192;
      short8 kf = *(const short8*)(Kt8 + ((0 * 2 + hi) * 64 + (b2 & 1) * 32 + ql) * 16);
      sv[b2] = __builtin_amdgcn_mfma_f32_32x32x16_bf16(kf, qf[0], z16, 0, 0, 0);
    }
#pragma unroll
    for (int c = 1; c < 4; ++c) {
#pragma unroll
      for (int b2 = 0; b2 < 4; ++b2) {
        const char* Kt8 = Kc + (b2 >> 1) * 8192;
        short8 kf = *(const short8*)(Kt8 + ((c * 2 + hi) * 64 + (b2 & 1) * 32 + ql) * 16);
        sv[b2] = __builtin_amdgcn_mfma_f32_32x32x16_bf16(kf, qf[c], sv[b2], 0, 0, 0);
      }
    }

    // fixed-max softmax numerator: P = exp2(S), native v_exp_f32
#pragma unroll
    for (int b2 = 0; b2 < 4; ++b2)
#pragma unroll
      for (int r = 0; r < 16; ++r) sv[b2][r] = __builtin_amdgcn_exp2f(sv[b2][r]);

    // intervention: halve P for global key 0 (numerator only); save full P0
    if (it == 0 && hi == 0) { p0 = sv[0][0]; sv[0][0] *= 0.5f; }

    // pack P to bf16 pairs
    unsigned int pk[4][4][2];
#pragma unroll
    for (int b2 = 0; b2 < 4; ++b2)
#pragma unroll
      for (int R = 0; R < 4; ++R) {
        pk[b2][R][0] = cvtpk(sv[b2][4 * R + 0], sv[b2][4 * R + 1]);
        pk[b2][R][1] = cvtpk(sv[b2][4 * R + 2], sv[b2][4 * R + 3]);
      }

    // PV + row-sum via permlane32_swap A-fragments; kc = 16-key chunk 0..7
#pragma unroll
    for (int kc = 0; kc < 8; ++kc) {
      const int b2 = kc >> 1, Rl = 2 * (kc & 1);
      int2v sw0 = pl32swap(pk[b2][Rl][0], pk[b2][Rl + 1][0]);
      int2v sw1 = pl32swap(pk[b2][Rl][1], pk[b2][Rl + 1][1]);
      union { int i[4]; short8 v; } pa;
      pa.i[0] = sw0[0]; pa.i[1] = sw1[0]; pa.i[2] = sw0[1]; pa.i[3] = sw1[1];
      lacc = __builtin_amdgcn_mfma_f32_32x32x16_bf16(pa.v, ones.v, lacc, 0, 0, 0);
      const char* Vt8 = Vc + (kc >> 2) * 8192;
#pragma unroll
      for (int n = 0; n < 2; ++n) {
        short8 vb = *(const short8*)(Vt8 + (((kc & 3) * 2 + hi) * 64 + n * 32 + ql) * 16);
        oacc[n] = __builtin_amdgcn_mfma_f32_32x32x16_bf16(pa.v, vb, oacc[n], 0, 0, 0);
      }
    }

    __syncthreads();
    cur ^= 1;
  }

  // epilogue: normalize (denominator = lacc + 0.5*p0) and write AO directly
#pragma unroll
  for (int r = 0; r < 16; ++r) {
    const int qrow = (r & 3) + 8 * (r >> 2) + 4 * hi;
    const float lv = lacc[r] + 0.5f * __shfl(p0, qrow);
    const float inv = 1.0f / lv;
#pragma unroll
    for (int n = 0; n < 2; ++n) {
      AO[(size_t)(b * LSEQ + q0 + qrow) * DMODEL + h * 64 + n * 32 + ql] =
          f2b(oacc[n][r] * inv);
    }
  }
}

// out = AO @ Wo^T + bo. BM=128 x BN=64 tile -> grid (32,16) = 512 blocks =
// 2 blocks/CU. Wo is L2-resident so the extra B-panel re-reads are cheap.
__global__ __launch_bounds__(256, 2) void k_gemm_out(
    const unsigned short* __restrict__ AO, const unsigned short* __restrict__ Wob,
    const float* __restrict__ bo, float* __restrict__ out)
{
  __shared__ char As[16384];   // 128 x 64 bf16
  __shared__ char Bs[8192];    // 64 x 64 bf16
  const int rowBase = blockIdx.x * 128, colBase = blockIdx.y * 64;
  const int tid  = threadIdx.x;
  const int lane = tid & 63;
  const int wr   = tid >> 7;
  const int wc   = (tid >> 6) & 1;

  f32x4 zero = {0.f, 0.f, 0.f, 0.f};
  f32x4 acc[4][2];
#pragma unroll
  for (int m = 0; m < 4; ++m)
#pragma unroll
    for (int n = 0; n < 2; ++n) acc[m][n] = zero;

  for (int kt = 0; kt < DMODEL / 64; ++kt) {
    const int k0 = kt * 64;
    __syncthreads();
#pragma unroll
    for (int p = 0; p < 4; ++p) {
      const int chunk = p * 256 + tid;
      const int row   = chunk >> 3;
      const int cs    = (chunk & 7) ^ (row & 7);
      async16(AO + (size_t)(rowBase + row) * DMODEL + k0 + cs * 8,
              As + (p * 256 + (tid & 0xC0)) * 16);
    }
#pragma unroll
    for (int p = 0; p < 2; ++p) {
      const int chunk = p * 256 + tid;
      const int row   = chunk >> 3;
      const int cs    = (chunk & 7) ^ (row & 7);
      async16(Wob + (size_t)(colBase + row) * DMODEL + k0 + cs * 8,
              Bs + (p * 256 + (tid & 0xC0)) * 16);
    }
    __syncthreads();
#pragma unroll
    for (int ks = 0; ks < 2; ++ks) {
      short8 af[4], bfr[2];
#pragma unroll
      for (int m = 0; m < 4; ++m) {
        const int ra = wr * 64 + m * 16 + (lane & 15);
        af[m] = *(const short8*)(As + ra * 128 + (((ks * 4 + (lane >> 4)) ^ (ra & 7)) * 16));
      }
#pragma unroll
      for (int n = 0; n < 2; ++n) {
        const int rb = wc * 32 + n * 16 + (lane & 15);
        bfr[n] = *(const short8*)(Bs + rb * 128 + (((ks * 4 + (lane >> 4)) ^ (rb & 7)) * 16));
      }
#pragma unroll
      for (int m = 0; m < 4; ++m)
#pragma unroll
        for (int n = 0; n < 2; ++n)
          acc[m][n] = __builtin_amdgcn_mfma_f32_16x16x32_bf16(af[m], bfr[n], acc[m][n], 0, 0, 0);
    }
  }

#pragma unroll
  for (int m = 0; m < 4; ++m) {
#pragma unroll
    for (int n = 0; n < 2; ++n) {
      const int gcol = colBase + wc * 32 + n * 16 + (lane & 15);
      const float bb = bo[gcol];
#pragma unroll
      for (int r = 0; r < 4; ++r) {
        const int grow = rowBase + wr * 64 + m * 16 + ((lane >> 4) << 2) + r;
        out[(size_t)grow * DMODEL + gcol] = acc[m][n][r] + bb;
      }
    }
  }
}

extern "C" void kernel_launch(void* const* d_in, const int* in_sizes, int n_in,
                              void* d_out, int out_size, void* d_ws, size_t ws_size,
                              hipStream_t stream) {
  const float* x  = (const float*)d_in[0];
  const float* Wq = (const float*)d_in[1];
  const float* bq = (const float*)d_in[2];
  const float* Wk = (const float*)d_in[3];
  const float* bk = (const float*)d_in[4];
  const float* Wv = (const float*)d_in[5];
  const float* bv = (const float*)d_in[6];
  const float* Wo = (const float*)d_in[7];
  const float* bo = (const float*)d_in[8];
  float* out = (float*)d_out;
  char* ws = (char*)d_ws;

  const size_t MB = 1u << 20;
  unsigned short* xb  = (unsigned short*)(ws);             // 0-8  (dead after qkv)
  unsigned short* AOb = (unsigned short*)(ws);             // reuse xb slot post-qkv
  unsigned short* Wob = (unsigned short*)(ws + 8  * MB);   // 8-10 (live to end)
  unsigned short* Wqb = (unsigned short*)(ws + 10 * MB);   // 10-12
  unsigned short* Wkb = (unsigned short*)(ws + 12 * MB);   // 12-14
  unsigned short* Wvb = (unsigned short*)(ws + 14 * MB);   // 14-16
  unsigned short* Qb  = (unsigned short*)(ws + 16 * MB);   // 16-24
  unsigned short* Ksw = (unsigned short*)(ws + 24 * MB);   // 24-32
  unsigned short* Vsw = (unsigned short*)(ws + 32 * MB);   // 32-40

  dim3 gcv(1024, 8);
  k_cvtall<<<gcv, 256, 0, stream>>>(x, Wq, Wk, Wv, Wo, xb, Wqb, Wkb, Wvb, Wob);

  dim3 gqkv(MROWS / 128, DMODEL / 128, 3);
  k_gemm_qkv<<<gqkv, 256, 0, stream>>>(xb, Wqb, Wkb, Wvb, bq, bk, bv, Qb, Ksw, Vsw);

  k_attn<<<16 * 32, 256, 0, stream>>>(Qb, Ksw, Vsw, AOb);

  dim3 gout(MROWS / 128, DMODEL / 64);
  k_gemm_out<<<gout, 256, 0, stream>>>(AOb, Wob, bo, out);
}

// Round 17
// 102.294 us; speedup vs baseline: 1.2985x; 1.0275x over previous
//
#include <hip/hip_runtime.h>
#include <stdint.h>

#define DMODEL 1024
#define LSEQ   2048
#define NBATCH 2
#define NHEADS 16
#define DKH    64
#define MROWS  4096  // NBATCH*LSEQ

typedef __attribute__((ext_vector_type(8))) short short8;
typedef __attribute__((ext_vector_type(4))) float f32x4;
typedef __attribute__((ext_vector_type(16))) float f32x16;
typedef __attribute__((ext_vector_type(2))) int int2v;

__device__ __forceinline__ unsigned short f2b(float f) {
  union { float f; unsigned int u; } v; v.f = f;
  unsigned int r = v.u + 0x7FFFu + ((v.u >> 16) & 1u);
  return (unsigned short)(r >> 16);
}

__device__ __forceinline__ float b2f(unsigned short u) {
  union { unsigned int i; float f; } v; v.i = ((unsigned int)u) << 16; return v.f;
}

__device__ __forceinline__ unsigned int cvtpk(float lo, float hi) {
  unsigned int r;
  asm volatile("v_cvt_pk_bf16_f32 %0, %1, %2" : "=v"(r) : "v"(lo), "v"(hi));
  return r;
}

__device__ __forceinline__ int2v pl32swap(unsigned int a, unsigned int b) {
  return __builtin_amdgcn_permlane32_swap((int)a, (int)b, false, false);
}

__device__ __forceinline__ void async16(const void* g, void* l) {
  __builtin_amdgcn_global_load_lds(
      (const __attribute__((address_space(1))) unsigned int*)g,
      (__attribute__((address_space(3))) unsigned int*)l, 16, 0, 0);
}

// one launch converts x (4 slices) + 4 weight matrices; each slice = 1M floats
__global__ void k_cvtall(const float* __restrict__ x,
                         const float* __restrict__ w0, const float* __restrict__ w1,
                         const float* __restrict__ w2, const float* __restrict__ w3,
                         unsigned short* __restrict__ xb,
                         unsigned short* __restrict__ d0, unsigned short* __restrict__ d1,
                         unsigned short* __restrict__ d2, unsigned short* __restrict__ d3) {
  const int y = blockIdx.y;
  const float* s; unsigned short* d;
  switch (y) {
    case 0: case 1: case 2: case 3:
      s = x + (size_t)y * 1048576; d = xb + (size_t)y * 1048576; break;
    case 4: s = w0; d = d0; break;
    case 5: s = w1; d = d1; break;
    case 6: s = w2; d = d2; break;
    default: s = w3; d = d3; break;
  }
  const int i = blockIdx.x * blockDim.x + threadIdx.x;
  float4 v = ((const float4*)s)[i];
  ushort4 o;
  o.x = f2b(v.x); o.y = f2b(v.y); o.z = f2b(v.z); o.w = f2b(v.w);
  ((ushort4*)d)[i] = o;
}

// acc += A[rowBase:+128, :] @ B[colBase:+128, :]^T  (both row-major [*,1024] bf16)
__device__ __forceinline__ void gemm_mainloop(
    const unsigned short* __restrict__ A, const unsigned short* __restrict__ B,
    int rowBase, int colBase, char* As, char* Bs, f32x4 acc[4][4])
{
  const int tid  = threadIdx.x;
  const int lane = tid & 63;
  const int wr   = tid >> 7;
  const int wc   = (tid >> 6) & 1;
  for (int kt = 0; kt < DMODEL / 64; ++kt) {
    const int k0 = kt * 64;
    __syncthreads();
#pragma unroll
    for (int p = 0; p < 4; ++p) {
      const int chunk = p * 256 + tid;
      const int row   = chunk >> 3;
      const int cs    = (chunk & 7) ^ (row & 7);
      async16(A + (size_t)(rowBase + row) * DMODEL + k0 + cs * 8,
              As + (p * 256 + (tid & 0xC0)) * 16);
      async16(B + (size_t)(colBase + row) * DMODEL + k0 + cs * 8,
              Bs + (p * 256 + (tid & 0xC0)) * 16);
    }
    __syncthreads();
#pragma unroll
    for (int ks = 0; ks < 2; ++ks) {
      short8 af[4], bfr[4];
#pragma unroll
      for (int m = 0; m < 4; ++m) {
        const int ra = wr * 64 + m * 16 + (lane & 15);
        af[m]  = *(const short8*)(As + ra * 128 + (((ks * 4 + (lane >> 4)) ^ (ra & 7)) * 16));
        const int rb = wc * 64 + m * 16 + (lane & 15);
        bfr[m] = *(const short8*)(Bs + rb * 128 + (((ks * 4 + (lane >> 4)) ^ (rb & 7)) * 16));
      }
#pragma unroll
      for (int m = 0; m < 4; ++m)
#pragma unroll
        for (int n = 0; n < 4; ++n)
          acc[m][n] = __builtin_amdgcn_mfma_f32_16x16x32_bf16(af[m], bfr[n], acc[m][n], 0, 0, 0);
    }
  }
}

// z=0: Q (scaled by 0.125*log2e) -> [bh][l][dk] row-major
// z=1: K -> tiled [bh][l/64][dchunk=0..7][row=l&63] 16B chunks
// z=2: V -> tiled [bh][l/64][kchunk=0..7][row=dk]   16B chunks
__global__ __launch_bounds__(256, 2) void k_gemm_qkv(
    const unsigned short* __restrict__ xb,
    const unsigned short* __restrict__ Wqb, const unsigned short* __restrict__ Wkb,
    const unsigned short* __restrict__ Wvb,
    const float* __restrict__ bq, const float* __restrict__ bk, const float* __restrict__ bv,
    unsigned short* __restrict__ Q, unsigned short* __restrict__ Ksw,
    unsigned short* __restrict__ Vsw)
{
  __shared__ char As[16384];
  __shared__ char Bs[16384];
  const int z = blockIdx.z;
  const unsigned short* W = (z == 0) ? Wqb : ((z == 1) ? Wkb : Wvb);
  const float* bias       = (z == 0) ? bq  : ((z == 1) ? bk  : bv);
  const int rowBase = blockIdx.x * 128, colBase = blockIdx.y * 128;

  f32x4 zero = {0.f, 0.f, 0.f, 0.f};
  f32x4 acc[4][4];
#pragma unroll
  for (int m = 0; m < 4; ++m)
#pragma unroll
    for (int n = 0; n < 4; ++n) acc[m][n] = zero;

  gemm_mainloop(xb, W, rowBase, colBase, As, Bs, acc);

  const int tid = threadIdx.x, lane = tid & 63;
  const int wr = tid >> 7, wc = (tid >> 6) & 1;
  const float scale = (z == 0) ? 0.18033688011112042f : 1.0f; // 0.125*log2(e)
#pragma unroll
  for (int m = 0; m < 4; ++m) {
#pragma unroll
    for (int n = 0; n < 4; ++n) {
      const int gcol = colBase + wc * 64 + n * 16 + (lane & 15);
      const float bb = bias[gcol];
      const int h = gcol >> 6, d = gcol & 63;
      if (z == 0) {
#pragma unroll
        for (int r = 0; r < 4; ++r) {
          const int grow = rowBase + wr * 64 + m * 16 + ((lane >> 4) << 2) + r;
          const int bi = grow >> 11, l = grow & 2047;
          Q[(((size_t)(bi * NHEADS + h)) * LSEQ + l) * DKH + d] =
              f2b((acc[m][n][r] + bb) * scale);
        }
      } else if (z == 1) {
#pragma unroll
        for (int r = 0; r < 4; ++r) {
          const int grow = rowBase + wr * 64 + m * 16 + ((lane >> 4) << 2) + r;
          const int bi = grow >> 11, l = grow & 2047;
          const int bh = bi * NHEADS + h;
          Ksw[(size_t)(bh * 32 + (l >> 6)) * 4096 + ((d >> 3) * 64 + (l & 63)) * 8 + (d & 7)] =
              f2b(acc[m][n][r] + bb);
        }
      } else {
        const int grow0 = rowBase + wr * 64 + m * 16 + ((lane >> 4) << 2);
        const int bi = grow0 >> 11, l0 = grow0 & 2047;
        const int bh = bi * NHEADS + h;
        ushort4 o;
        o.x = f2b(acc[m][n][0] + bb);
        o.y = f2b(acc[m][n][1] + bb);
        o.z = f2b(acc[m][n][2] + bb);
        o.w = f2b(acc[m][n][3] + bb);
        *(ushort4*)(Vsw + (size_t)(bh * 32 + (l0 >> 6)) * 4096 +
                    (((l0 & 63) >> 3) * 64 + d) * 8 + (l0 & 7)) = o;
      }
    }
  }
}

// Flash attention, swapped-QK^T, fixed-max softmax (native v_exp_f32),
// MFMA row-sum, XCD-aware flat grid decode (T1). KVBLK=128, 8 waves/block,
// 256 q-rows per block: one stage serves 8 waves -> per-CU staging bytes,
// stage-issue and barrier count all halve vs the 4-wave variant.
__global__ __launch_bounds__(512, 2) void k_attn(
    const unsigned short* __restrict__ Q, const unsigned short* __restrict__ Ksw,
    const unsigned short* __restrict__ Vsw,
    unsigned short* __restrict__ AO)
{
  __shared__ char Ks[2][16384];   // 2 adjacent 64-key tiles, chunk-major each
  __shared__ char Vs[2][16384];

  const int tid = threadIdx.x, lane = tid & 63, w = tid >> 6;  // w = 0..7
  const int hi = lane >> 5;
  const int ql = lane & 31;

  const int flat = blockIdx.x;
  const int bh = flat & 31;       // bh group -> fixed XCD (flat mod 8)
  const int qi = flat >> 5;       // q-block 0..7 (256 rows each)
  const int b = bh >> 4, h = bh & 15;
  const int q0 = qi * 256 + w * 32;

  const unsigned short* __restrict__ Qh = Q + (size_t)bh * LSEQ * DKH;

  short8 qf[4];
#pragma unroll
  for (int c = 0; c < 4; ++c)
    qf[c] = *(const short8*)(Qh + (size_t)(q0 + ql) * DKH + c * 16 + hi * 8);

  // ones fragment for the row-sum MFMA
  union { unsigned short u[8]; short8 v; } ones;
#pragma unroll
  for (int j = 0; j < 8; ++j) ones.u[j] = 0x3F80;

  f32x16 oacc[2], lacc, z16;
#pragma unroll
  for (int r = 0; r < 16; ++r) {
    oacc[0][r] = 0.f; oacc[1][r] = 0.f; lacc[r] = 0.f; z16[r] = 0.f;
  }
  float p0 = 0.f;

  // stage two adjacent 64-key tiles (16 KB K + 16 KB V, fully linear),
  // 512 threads: 2 phases x (1 K + 1 V) async16 per thread
  auto stage = [&](int buf, int it2) {
    const unsigned short* Kt = Ksw + (size_t)(bh * 32 + it2 * 2) * 4096;
    const unsigned short* Vt = Vsw + (size_t)(bh * 32 + it2 * 2) * 4096;
#pragma unroll
    for (int p = 0; p < 2; ++p) {
      const int c = p * 512 + tid;
      async16(Kt + c * 8, Ks[buf] + (p * 512 + (tid & 0x1C0)) * 16);
      async16(Vt + c * 8, Vs[buf] + (p * 512 + (tid & 0x1C0)) * 16);
    }
  };

  const int NT = 16;   // 16 iterations x 128 keys

  stage(0, 0);
  __syncthreads();

  int cur = 0;
  for (int it = 0; it < NT; ++it) {
    if (it < NT - 1) stage(cur ^ 1, it + 1);
    const char* Kc = Ks[cur];
    const char* Vc = Vs[cur];

    // S^T = K Q^T over 128 keys: sv[b2] covers keys b2*32..b2*32+31
    f32x16 sv[4];
#pragma unroll
    for (int b2 = 0; b2 < 4; ++b2) {
      const char* Kt8 = Kc + (b2 >> 1) * 8192;
      short8 kf = *(const short8*)(Kt8 + ((0 * 2 + hi) * 64 + (b2 & 1) * 32 + ql) * 16);
      sv[b2] = __builtin_amdgcn_mfma_f32_32x32x16_bf16(kf, qf[0], z16, 0, 0, 0);
    }
#pragma unroll
    for (int c = 1; c < 4; ++c) {
#pragma unroll
      for (int b2 = 0; b2 < 4; ++b2) {
        const char* Kt8 = Kc + (b2 >> 1) * 8192;
        short8 kf = *(const short8*)(Kt8 + ((c * 2 + hi) * 64 + (b2 & 1) * 32 + ql) * 16);
        sv[b2] = __builtin_amdgcn_mfma_f32_32x32x16_bf16(kf, qf[c], sv[b2], 0, 0, 0);
      }
    }

    // fixed-max softmax numerator: P = exp2(S), native v_exp_f32
#pragma unroll
    for (int b2 = 0; b2 < 4; ++b2)
#pragma unroll
      for (int r = 0; r < 16; ++r) sv[b2][r] = __builtin_amdgcn_exp2f(sv[b2][r]);

    // intervention: halve P for global key 0 (numerator only); save full P0
    if (it == 0 && hi == 0) { p0 = sv[0][0]; sv[0][0] *= 0.5f; }

    // pack P to bf16 pairs
    unsigned int pk[4][4][2];
#pragma unroll
    for (int b2 = 0; b2 < 4; ++b2)
#pragma unroll
      for (int R = 0; R < 4; ++R) {
        pk[b2][R][0] = cvtpk(sv[b2][4 * R + 0], sv[b2][4 * R + 1]);
        pk[b2][R][1] = cvtpk(sv[b2][4 * R + 2], sv[b2][4 * R + 3]);
      }

    // PV + row-sum via permlane32_swap A-fragments; kc = 16-key chunk 0..7
#pragma unroll
    for (int kc = 0; kc < 8; ++kc) {
      const int b2 = kc >> 1, Rl = 2 * (kc & 1);
      int2v sw0 = pl32swap(pk[b2][Rl][0], pk[b2][Rl + 1][0]);
      int2v sw1 = pl32swap(pk[b2][Rl][1], pk[b2][Rl + 1][1]);
      union { int i[4]; short8 v; } pa;
      pa.i[0] = sw0[0]; pa.i[1] = sw1[0]; pa.i[2] = sw0[1]; pa.i[3] = sw1[1];
      lacc = __builtin_amdgcn_mfma_f32_32x32x16_bf16(pa.v, ones.v, lacc, 0, 0, 0);
      const char* Vt8 = Vc + (kc >> 2) * 8192;
#pragma unroll
      for (int n = 0; n < 2; ++n) {
        short8 vb = *(const short8*)(Vt8 + (((kc & 3) * 2 + hi) * 64 + n * 32 + ql) * 16);
        oacc[n] = __builtin_amdgcn_mfma_f32_32x32x16_bf16(pa.v, vb, oacc[n], 0, 0, 0);
      }
    }

    __syncthreads();
    cur ^= 1;
  }

  // epilogue: normalize (denominator = lacc + 0.5*p0) and write AO directly
#pragma unroll
  for (int r = 0; r < 16; ++r) {
    const int qrow = (r & 3) + 8 * (r >> 2) + 4 * hi;
    const float lv = lacc[r] + 0.5f * __shfl(p0, qrow);
    const float inv = 1.0f / lv;
#pragma unroll
    for (int n = 0; n < 2; ++n) {
      AO[(size_t)(b * LSEQ + q0 + qrow) * DMODEL + h * 64 + n * 32 + ql] =
          f2b(oacc[n][r] * inv);
    }
  }
}

// out = AO @ Wo^T + bo. BM=128 x BN=64 tile -> grid (32,16) = 512 blocks =
// 2 blocks/CU. Wo is L2-resident so the extra B-panel re-reads are cheap.
__global__ __launch_bounds__(256, 2) void k_gemm_out(
    const unsigned short* __restrict__ AO, const unsigned short* __restrict__ Wob,
    const float* __restrict__ bo, float* __restrict__ out)
{
  __shared__ char As[16384];   // 128 x 64 bf16
  __shared__ char Bs[8192];    // 64 x 64 bf16
  const int rowBase = blockIdx.x * 128, colBase = blockIdx.y * 64;
  const int tid  = threadIdx.x;
  const int lane = tid & 63;
  const int wr   = tid >> 7;
  const int wc   = (tid >> 6) & 1;

  f32x4 zero = {0.f, 0.f, 0.f, 0.f};
  f32x4 acc[4][2];
#pragma unroll
  for (int m = 0; m < 4; ++m)
#pragma unroll
    for (int n = 0; n < 2; ++n) acc[m][n] = zero;

  for (int kt = 0; kt < DMODEL / 64; ++kt) {
    const int k0 = kt * 64;
    __syncthreads();
#pragma unroll
    for (int p = 0; p < 4; ++p) {
      const int chunk = p * 256 + tid;
      const int row   = chunk >> 3;
      const int cs    = (chunk & 7) ^ (row & 7);
      async16(AO + (size_t)(rowBase + row) * DMODEL + k0 + cs * 8,
              As + (p * 256 + (tid & 0xC0)) * 16);
    }
#pragma unroll
    for (int p = 0; p < 2; ++p) {
      const int chunk = p * 256 + tid;
      const int row   = chunk >> 3;
      const int cs    = (chunk & 7) ^ (row & 7);
      async16(Wob + (size_t)(colBase + row) * DMODEL + k0 + cs * 8,
              Bs + (p * 256 + (tid & 0xC0)) * 16);
    }
    __syncthreads();
#pragma unroll
    for (int ks = 0; ks < 2; ++ks) {
      short8 af[4], bfr[2];
#pragma unroll
      for (int m = 0; m < 4; ++m) {
        const int ra = wr * 64 + m * 16 + (lane & 15);
        af[m] = *(const short8*)(As + ra * 128 + (((ks * 4 + (lane >> 4)) ^ (ra & 7)) * 16));
      }
#pragma unroll
      for (int n = 0; n < 2; ++n) {
        const int rb = wc * 32 + n * 16 + (lane & 15);
        bfr[n] = *(const short8*)(Bs + rb * 128 + (((ks * 4 + (lane >> 4)) ^ (rb & 7)) * 16));
      }
#pragma unroll
      for (int m = 0; m < 4; ++m)
#pragma unroll
        for (int n = 0; n < 2; ++n)
          acc[m][n] = __builtin_amdgcn_mfma_f32_16x16x32_bf16(af[m], bfr[n], acc[m][n], 0, 0, 0);
    }
  }

#pragma unroll
  for (int m = 0; m < 4; ++m) {
#pragma unroll
    for (int n = 0; n < 2; ++n) {
      const int gcol = colBase + wc * 32 + n * 16 + (lane & 15);
      const float bb = bo[gcol];
#pragma unroll
      for (int r = 0; r < 4; ++r) {
        const int grow = rowBase + wr * 64 + m * 16 + ((lane >> 4) << 2) + r;
        out[(size_t)grow * DMODEL + gcol] = acc[m][n][r] + bb;
      }
    }
  }
}

extern "C" void kernel_launch(void* const* d_in, const int* in_sizes, int n_in,
                              void* d_out, int out_size, void* d_ws, size_t ws_size,
                              hipStream_t stream) {
  const float* x  = (const float*)d_in[0];
  const float* Wq = (const float*)d_in[1];
  const float* bq = (const float*)d_in[2];
  const float* Wk = (const float*)d_in[3];
  const float* bk = (const float*)d_in[4];
  const float* Wv = (const float*)d_in[5];
  const float* bv = (const float*)d_in[6];
  const float* Wo = (const float*)d_in[7];
  const float* bo = (const float*)d_in[8];
  float* out = (float*)d_out;
  char* ws = (char*)d_ws;

  const size_t MB = 1u << 20;
  unsigned short* xb  = (unsigned short*)(ws);             // 0-8  (dead after qkv)
  unsigned short* AOb = (unsigned short*)(ws);             // reuse xb slot post-qkv
  unsigned short* Wob = (unsigned short*)(ws + 8  * MB);   // 8-10 (live to end)
  unsigned short* Wqb = (unsigned short*)(ws + 10 * MB);   // 10-12
  unsigned short* Wkb = (unsigned short*)(ws + 12 * MB);   // 12-14
  unsigned short* Wvb = (unsigned short*)(ws + 14 * MB);   // 14-16
  unsigned short* Qb  = (unsigned short*)(ws + 16 * MB);   // 16-24
  unsigned short* Ksw = (unsigned short*)(ws + 24 * MB);   // 24-32
  unsigned short* Vsw = (unsigned short*)(ws + 32 * MB);   // 32-40

  dim3 gcv(1024, 8);
  k_cvtall<<<gcv, 256, 0, stream>>>(x, Wq, Wk, Wv, Wo, xb, Wqb, Wkb, Wvb, Wob);

  dim3 gqkv(MROWS / 128, DMODEL / 128, 3);
  k_gemm_qkv<<<gqkv, 256, 0, stream>>>(xb, Wqb, Wkb, Wvb, bq, bk, bv, Qb, Ksw, Vsw);

  k_attn<<<8 * 32, 512, 0, stream>>>(Qb, Ksw, Vsw, AOb);

  dim3 gout(MROWS / 128, DMODEL / 64);
  k_gemm_out<<<gout, 256, 0, stream>>>(AOb, Wob, bo, out);
}

// Round 18
// 101.048 us; speedup vs baseline: 1.3145x; 1.0123x over previous
//
#include <hip/hip_runtime.h>
#include <stdint.h>

#define DMODEL 1024
#define LSEQ   2048
#define NBATCH 2
#define NHEADS 16
#define DKH    64
#define MROWS  4096  // NBATCH*LSEQ

typedef __attribute__((ext_vector_type(8))) short short8;
typedef __attribute__((ext_vector_type(4))) float f32x4;
typedef __attribute__((ext_vector_type(16))) float f32x16;
typedef __attribute__((ext_vector_type(2))) int int2v;

__device__ __forceinline__ unsigned short f2b(float f) {
  union { float f; unsigned int u; } v; v.f = f;
  unsigned int r = v.u + 0x7FFFu + ((v.u >> 16) & 1u);
  return (unsigned short)(r >> 16);
}

__device__ __forceinline__ float b2f(unsigned short u) {
  union { unsigned int i; float f; } v; v.i = ((unsigned int)u) << 16; return v.f;
}

__device__ __forceinline__ unsigned int cvtpk(float lo, float hi) {
  unsigned int r;
  asm volatile("v_cvt_pk_bf16_f32 %0, %1, %2" : "=v"(r) : "v"(lo), "v"(hi));
  return r;
}

__device__ __forceinline__ int2v pl32swap(unsigned int a, unsigned int b) {
  return __builtin_amdgcn_permlane32_swap((int)a, (int)b, false, false);
}

__device__ __forceinline__ void async16(const void* g, void* l) {
  __builtin_amdgcn_global_load_lds(
      (const __attribute__((address_space(1))) unsigned int*)g,
      (__attribute__((address_space(3))) unsigned int*)l, 16, 0, 0);
}

// one launch converts x (4 slices) + 4 weight matrices; each slice = 1M floats
__global__ void k_cvtall(const float* __restrict__ x,
                         const float* __restrict__ w0, const float* __restrict__ w1,
                         const float* __restrict__ w2, const float* __restrict__ w3,
                         unsigned short* __restrict__ xb,
                         unsigned short* __restrict__ d0, unsigned short* __restrict__ d1,
                         unsigned short* __restrict__ d2, unsigned short* __restrict__ d3) {
  const int y = blockIdx.y;
  const float* s; unsigned short* d;
  switch (y) {
    case 0: case 1: case 2: case 3:
      s = x + (size_t)y * 1048576; d = xb + (size_t)y * 1048576; break;
    case 4: s = w0; d = d0; break;
    case 5: s = w1; d = d1; break;
    case 6: s = w2; d = d2; break;
    default: s = w3; d = d3; break;
  }
  const int i = blockIdx.x * blockDim.x + threadIdx.x;
  float4 v = ((const float4*)s)[i];
  ushort4 o;
  o.x = f2b(v.x); o.y = f2b(v.y); o.z = f2b(v.z); o.w = f2b(v.w);
  ((ushort4*)d)[i] = o;
}

// acc += A[rowBase:+128, :] @ B[colBase:+128, :]^T  (both row-major [*,1024] bf16)
__device__ __forceinline__ void gemm_mainloop(
    const unsigned short* __restrict__ A, const unsigned short* __restrict__ B,
    int rowBase, int colBase, char* As, char* Bs, f32x4 acc[4][4])
{
  const int tid  = threadIdx.x;
  const int lane = tid & 63;
  const int wr   = tid >> 7;
  const int wc   = (tid >> 6) & 1;
  for (int kt = 0; kt < DMODEL / 64; ++kt) {
    const int k0 = kt * 64;
    __syncthreads();
#pragma unroll
    for (int p = 0; p < 4; ++p) {
      const int chunk = p * 256 + tid;
      const int row   = chunk >> 3;
      const int cs    = (chunk & 7) ^ (row & 7);
      async16(A + (size_t)(rowBase + row) * DMODEL + k0 + cs * 8,
              As + (p * 256 + (tid & 0xC0)) * 16);
      async16(B + (size_t)(colBase + row) * DMODEL + k0 + cs * 8,
              Bs + (p * 256 + (tid & 0xC0)) * 16);
    }
    __syncthreads();
#pragma unroll
    for (int ks = 0; ks < 2; ++ks) {
      short8 af[4], bfr[4];
#pragma unroll
      for (int m = 0; m < 4; ++m) {
        const int ra = wr * 64 + m * 16 + (lane & 15);
        af[m]  = *(const short8*)(As + ra * 128 + (((ks * 4 + (lane >> 4)) ^ (ra & 7)) * 16));
        const int rb = wc * 64 + m * 16 + (lane & 15);
        bfr[m] = *(const short8*)(Bs + rb * 128 + (((ks * 4 + (lane >> 4)) ^ (rb & 7)) * 16));
      }
#pragma unroll
      for (int m = 0; m < 4; ++m)
#pragma unroll
        for (int n = 0; n < 4; ++n)
          acc[m][n] = __builtin_amdgcn_mfma_f32_16x16x32_bf16(af[m], bfr[n], acc[m][n], 0, 0, 0);
    }
  }
}

// z=0: Q (scaled by 0.125*log2e) -> [bh][l][dk] row-major
// z=1: K -> tiled [bh][l/64][dchunk=0..7][row=l&63] 16B chunks
// z=2: V -> tiled [bh][l/64][kchunk=0..7][row=dk]   16B chunks
__global__ __launch_bounds__(256, 2) void k_gemm_qkv(
    const unsigned short* __restrict__ xb,
    const unsigned short* __restrict__ Wqb, const unsigned short* __restrict__ Wkb,
    const unsigned short* __restrict__ Wvb,
    const float* __restrict__ bq, const float* __restrict__ bk, const float* __restrict__ bv,
    unsigned short* __restrict__ Q, unsigned short* __restrict__ Ksw,
    unsigned short* __restrict__ Vsw)
{
  __shared__ char As[16384];
  __shared__ char Bs[16384];
  const int z = blockIdx.z;
  const unsigned short* W = (z == 0) ? Wqb : ((z == 1) ? Wkb : Wvb);
  const float* bias       = (z == 0) ? bq  : ((z == 1) ? bk  : bv);
  const int rowBase = blockIdx.x * 128, colBase = blockIdx.y * 128;

  f32x4 zero = {0.f, 0.f, 0.f, 0.f};
  f32x4 acc[4][4];
#pragma unroll
  for (int m = 0; m < 4; ++m)
#pragma unroll
    for (int n = 0; n < 4; ++n) acc[m][n] = zero;

  gemm_mainloop(xb, W, rowBase, colBase, As, Bs, acc);

  const int tid = threadIdx.x, lane = tid & 63;
  const int wr = tid >> 7, wc = (tid >> 6) & 1;
  const float scale = (z == 0) ? 0.18033688011112042f : 1.0f; // 0.125*log2(e)
#pragma unroll
  for (int m = 0; m < 4; ++m) {
#pragma unroll
    for (int n = 0; n < 4; ++n) {
      const int gcol = colBase + wc * 64 + n * 16 + (lane & 15);
      const float bb = bias[gcol];
      const int h = gcol >> 6, d = gcol & 63;
      if (z == 0) {
#pragma unroll
        for (int r = 0; r < 4; ++r) {
          const int grow = rowBase + wr * 64 + m * 16 + ((lane >> 4) << 2) + r;
          const int bi = grow >> 11, l = grow & 2047;
          Q[(((size_t)(bi * NHEADS + h)) * LSEQ + l) * DKH + d] =
              f2b((acc[m][n][r] + bb) * scale);
        }
      } else if (z == 1) {
#pragma unroll
        for (int r = 0; r < 4; ++r) {
          const int grow = rowBase + wr * 64 + m * 16 + ((lane >> 4) << 2) + r;
          const int bi = grow >> 11, l = grow & 2047;
          const int bh = bi * NHEADS + h;
          Ksw[(size_t)(bh * 32 + (l >> 6)) * 4096 + ((d >> 3) * 64 + (l & 63)) * 8 + (d & 7)] =
              f2b(acc[m][n][r] + bb);
        }
      } else {
        const int grow0 = rowBase + wr * 64 + m * 16 + ((lane >> 4) << 2);
        const int bi = grow0 >> 11, l0 = grow0 & 2047;
        const int bh = bi * NHEADS + h;
        ushort4 o;
        o.x = f2b(acc[m][n][0] + bb);
        o.y = f2b(acc[m][n][1] + bb);
        o.z = f2b(acc[m][n][2] + bb);
        o.w = f2b(acc[m][n][3] + bb);
        *(ushort4*)(Vsw + (size_t)(bh * 32 + (l0 >> 6)) * 4096 +
                    (((l0 & 63) >> 3) * 64 + d) * 8 + (l0 & 7)) = o;
      }
    }
  }
}

// Flash attention, swapped-QK^T, fixed-max softmax (native v_exp_f32),
// MFMA row-sum, XCD-aware flat grid decode (T1). KVBLK=256: one stage +
// one barrier covers FOUR 64-key tiles, processed as two sequential 128-key
// halves that reuse the same sv/pk registers (8 iterations total, was 16).
// QK^T(half1) is independent of PV(half0) -> free intra-iteration interleave.
__global__ __launch_bounds__(512, 1) void k_attn(
    const unsigned short* __restrict__ Q, const unsigned short* __restrict__ Ksw,
    const unsigned short* __restrict__ Vsw,
    unsigned short* __restrict__ AO)
{
  __shared__ char Ks[2][32768];   // 4 adjacent 64-key tiles, chunk-major each
  __shared__ char Vs[2][32768];

  const int tid = threadIdx.x, lane = tid & 63, w = tid >> 6;  // w = 0..7
  const int hi = lane >> 5;
  const int ql = lane & 31;

  const int flat = blockIdx.x;
  const int bh = flat & 31;       // bh group -> fixed XCD (flat mod 8)
  const int qi = flat >> 5;       // q-block 0..7 (256 rows each)
  const int b = bh >> 4, h = bh & 15;
  const int q0 = qi * 256 + w * 32;

  const unsigned short* __restrict__ Qh = Q + (size_t)bh * LSEQ * DKH;

  short8 qf[4];
#pragma unroll
  for (int c = 0; c < 4; ++c)
    qf[c] = *(const short8*)(Qh + (size_t)(q0 + ql) * DKH + c * 16 + hi * 8);

  // ones fragment for the row-sum MFMA
  union { unsigned short u[8]; short8 v; } ones;
#pragma unroll
  for (int j = 0; j < 8; ++j) ones.u[j] = 0x3F80;

  f32x16 oacc[2], lacc, z16;
#pragma unroll
  for (int r = 0; r < 16; ++r) {
    oacc[0][r] = 0.f; oacc[1][r] = 0.f; lacc[r] = 0.f; z16[r] = 0.f;
  }
  float p0 = 0.f;

  // stage four adjacent 64-key tiles (32 KB K + 32 KB V, fully linear),
  // 512 threads: 4 phases x (1 K + 1 V) async16 per thread
  auto stage = [&](int buf, int it2) {
    const unsigned short* Kt = Ksw + (size_t)(bh * 32 + it2 * 4) * 4096;
    const unsigned short* Vt = Vsw + (size_t)(bh * 32 + it2 * 4) * 4096;
#pragma unroll
    for (int p = 0; p < 4; ++p) {
      const int c = p * 512 + tid;
      async16(Kt + c * 8, Ks[buf] + (p * 512 + (tid & 0x1C0)) * 16);
      async16(Vt + c * 8, Vs[buf] + (p * 512 + (tid & 0x1C0)) * 16);
    }
  };

  const int NT = 8;   // 8 iterations x 256 keys

  stage(0, 0);
  __syncthreads();

  int cur = 0;
  for (int it = 0; it < NT; ++it) {
    if (it < NT - 1) stage(cur ^ 1, it + 1);

#pragma unroll
    for (int half = 0; half < 2; ++half) {
      const char* Kc = Ks[cur] + half * 16384;
      const char* Vc = Vs[cur] + half * 16384;

      // S^T = K Q^T over 128 keys: sv[b2] covers keys b2*32..b2*32+31
      f32x16 sv[4];
#pragma unroll
      for (int b2 = 0; b2 < 4; ++b2) {
        const char* Kt8 = Kc + (b2 >> 1) * 8192;
        short8 kf = *(const short8*)(Kt8 + ((0 * 2 + hi) * 64 + (b2 & 1) * 32 + ql) * 16);
        sv[b2] = __builtin_amdgcn_mfma_f32_32x32x16_bf16(kf, qf[0], z16, 0, 0, 0);
      }
#pragma unroll
      for (int c = 1; c < 4; ++c) {
#pragma unroll
        for (int b2 = 0; b2 < 4; ++b2) {
          const char* Kt8 = Kc + (b2 >> 1) * 8192;
          short8 kf = *(const short8*)(Kt8 + ((c * 2 + hi) * 64 + (b2 & 1) * 32 + ql) * 16);
          sv[b2] = __builtin_amdgcn_mfma_f32_32x32x16_bf16(kf, qf[c], sv[b2], 0, 0, 0);
        }
      }

      // fixed-max softmax numerator: P = exp2(S), native v_exp_f32
#pragma unroll
      for (int b2 = 0; b2 < 4; ++b2)
#pragma unroll
        for (int r = 0; r < 16; ++r) sv[b2][r] = __builtin_amdgcn_exp2f(sv[b2][r]);

      // intervention: halve P for global key 0 (numerator only); save full P0
      if (it == 0 && half == 0 && hi == 0) { p0 = sv[0][0]; sv[0][0] *= 0.5f; }

      // pack P to bf16 pairs
      unsigned int pk[4][4][2];
#pragma unroll
      for (int b2 = 0; b2 < 4; ++b2)
#pragma unroll
        for (int R = 0; R < 4; ++R) {
          pk[b2][R][0] = cvtpk(sv[b2][4 * R + 0], sv[b2][4 * R + 1]);
          pk[b2][R][1] = cvtpk(sv[b2][4 * R + 2], sv[b2][4 * R + 3]);
        }

      // PV + row-sum via permlane32_swap A-fragments; kc = 16-key chunk 0..7
#pragma unroll
      for (int kc = 0; kc < 8; ++kc) {
        const int b2 = kc >> 1, Rl = 2 * (kc & 1);
        int2v sw0 = pl32swap(pk[b2][Rl][0], pk[b2][Rl + 1][0]);
        int2v sw1 = pl32swap(pk[b2][Rl][1], pk[b2][Rl + 1][1]);
        union { int i[4]; short8 v; } pa;
        pa.i[0] = sw0[0]; pa.i[1] = sw1[0]; pa.i[2] = sw0[1]; pa.i[3] = sw1[1];
        lacc = __builtin_amdgcn_mfma_f32_32x32x16_bf16(pa.v, ones.v, lacc, 0, 0, 0);
        const char* Vt8 = Vc + (kc >> 2) * 8192;
#pragma unroll
        for (int n = 0; n < 2; ++n) {
          short8 vb = *(const short8*)(Vt8 + (((kc & 3) * 2 + hi) * 64 + n * 32 + ql) * 16);
          oacc[n] = __builtin_amdgcn_mfma_f32_32x32x16_bf16(pa.v, vb, oacc[n], 0, 0, 0);
        }
      }
    }

    __syncthreads();
    cur ^= 1;
  }

  // epilogue: normalize (denominator = lacc + 0.5*p0) and write AO directly
#pragma unroll
  for (int r = 0; r < 16; ++r) {
    const int qrow = (r & 3) + 8 * (r >> 2) + 4 * hi;
    const float lv = lacc[r] + 0.5f * __shfl(p0, qrow);
    const float inv = 1.0f / lv;
#pragma unroll
    for (int n = 0; n < 2; ++n) {
      AO[(size_t)(b * LSEQ + q0 + qrow) * DMODEL + h * 64 + n * 32 + ql] =
          f2b(oacc[n][r] * inv);
    }
  }
}

// out = AO @ Wo^T + bo. BM=128 x BN=64 tile -> grid (32,16) = 512 blocks =
// 2 blocks/CU. Wo is L2-resident so the extra B-panel re-reads are cheap.
__global__ __launch_bounds__(256, 2) void k_gemm_out(
    const unsigned short* __restrict__ AO, const unsigned short* __restrict__ Wob,
    const float* __restrict__ bo, float* __restrict__ out)
{
  __shared__ char As[16384];   // 128 x 64 bf16
  __shared__ char Bs[8192];    // 64 x 64 bf16
  const int rowBase = blockIdx.x * 128, colBase = blockIdx.y * 64;
  const int tid  = threadIdx.x;
  const int lane = tid & 63;
  const int wr   = tid >> 7;
  const int wc   = (tid >> 6) & 1;

  f32x4 zero = {0.f, 0.f, 0.f, 0.f};
  f32x4 acc[4][2];
#pragma unroll
  for (int m = 0; m < 4; ++m)
#pragma unroll
    for (int n = 0; n < 2; ++n) acc[m][n] = zero;

  for (int kt = 0; kt < DMODEL / 64; ++kt) {
    const int k0 = kt * 64;
    __syncthreads();
#pragma unroll
    for (int p = 0; p < 4; ++p) {
      const int chunk = p * 256 + tid;
      const int row   = chunk >> 3;
      const int cs    = (chunk & 7) ^ (row & 7);
      async16(AO + (size_t)(rowBase + row) * DMODEL + k0 + cs * 8,
              As + (p * 256 + (tid & 0xC0)) * 16);
    }
#pragma unroll
    for (int p = 0; p < 2; ++p) {
      const int chunk = p * 256 + tid;
      const int row   = chunk >> 3;
      const int cs    = (chunk & 7) ^ (row & 7);
      async16(Wob + (size_t)(colBase + row) * DMODEL + k0 + cs * 8,
              Bs + (p * 256 + (tid & 0xC0)) * 16);
    }
    __syncthreads();
#pragma unroll
    for (int ks = 0; ks < 2; ++ks) {
      short8 af[4], bfr[2];
#pragma unroll
      for (int m = 0; m < 4; ++m) {
        const int ra = wr * 64 + m * 16 + (lane & 15);
        af[m] = *(const short8*)(As + ra * 128 + (((ks * 4 + (lane >> 4)) ^ (ra & 7)) * 16));
      }
#pragma unroll
      for (int n = 0; n < 2; ++n) {
        const int rb = wc * 32 + n * 16 + (lane & 15);
        bfr[n] = *(const short8*)(Bs + rb * 128 + (((ks * 4 + (lane >> 4)) ^ (rb & 7)) * 16));
      }
#pragma unroll
      for (int m = 0; m < 4; ++m)
#pragma unroll
        for (int n = 0; n < 2; ++n)
          acc[m][n] = __builtin_amdgcn_mfma_f32_16x16x32_bf16(af[m], bfr[n], acc[m][n], 0, 0, 0);
    }
  }

#pragma unroll
  for (int m = 0; m < 4; ++m) {
#pragma unroll
    for (int n = 0; n < 2; ++n) {
      const int gcol = colBase + wc * 32 + n * 16 + (lane & 15);
      const float bb = bo[gcol];
#pragma unroll
      for (int r = 0; r < 4; ++r) {
        const int grow = rowBase + wr * 64 + m * 16 + ((lane >> 4) << 2) + r;
        out[(size_t)grow * DMODEL + gcol] = acc[m][n][r] + bb;
      }
    }
  }
}

extern "C" void kernel_launch(void* const* d_in, const int* in_sizes, int n_in,
                              void* d_out, int out_size, void* d_ws, size_t ws_size,
                              hipStream_t stream) {
  const float* x  = (const float*)d_in[0];
  const float* Wq = (const float*)d_in[1];
  const float* bq = (const float*)d_in[2];
  const float* Wk = (const float*)d_in[3];
  const float* bk = (const float*)d_in[4];
  const float* Wv = (const float*)d_in[5];
  const float* bv = (const float*)d_in[6];
  const float* Wo = (const float*)d_in[7];
  const float* bo = (const float*)d_in[8];
  float* out = (float*)d_out;
  char* ws = (char*)d_ws;

  const size_t MB = 1u << 20;
  unsigned short* xb  = (unsigned short*)(ws);             // 0-8  (dead after qkv)
  unsigned short* AOb = (unsigned short*)(ws);             // reuse xb slot post-qkv
  unsigned short* Wob = (unsigned short*)(ws + 8  * MB);   // 8-10 (live to end)
  unsigned short* Wqb = (unsigned short*)(ws + 10 * MB);   // 10-12
  unsigned short* Wkb = (unsigned short*)(ws + 12 * MB);   // 12-14
  unsigned short* Wvb = (unsigned short*)(ws + 14 * MB);   // 14-16
  unsigned short* Qb  = (unsigned short*)(ws + 16 * MB);   // 16-24
  unsigned short* Ksw = (unsigned short*)(ws + 24 * MB);   // 24-32
  unsigned short* Vsw = (unsigned short*)(ws + 32 * MB);   // 32-40

  dim3 gcv(1024, 8);
  k_cvtall<<<gcv, 256, 0, stream>>>(x, Wq, Wk, Wv, Wo, xb, Wqb, Wkb, Wvb, Wob);

  dim3 gqkv(MROWS / 128, DMODEL / 128, 3);
  k_gemm_qkv<<<gqkv, 256, 0, stream>>>(xb, Wqb, Wkb, Wvb, bq, bk, bv, Qb, Ksw, Vsw);

  k_attn<<<8 * 32, 512, 0, stream>>>(Qb, Ksw, Vsw, AOb);

  dim3 gout(MROWS / 128, DMODEL / 64);
  k_gemm_out<<<gout, 256, 0, stream>>>(AOb, Wob, bo, out);
}